// Round 4
// baseline (142.256 us; speedup 1.0000x reference)
//
#include <hip/hip_runtime.h>

typedef _Float16 half8 __attribute__((ext_vector_type(8)));
typedef _Float16 half4 __attribute__((ext_vector_type(4)));
typedef float f32x4 __attribute__((ext_vector_type(4)));

#define S_LEN 2048
#define HDIM 64
#define QBLK 64
#define KVBLK 64
#define NT (S_LEN / KVBLK)
#define QRS 258
#define NBH 16
#define L2E 1.44269504f
#define TSTR 72

// ---- fused pre-pass ----------------------------------------------------------------
// blocks 0..1023: K fp32 -> Kh fp16 row-major passthrough (elementwise convert).
// blocks 1024..1535: V fp32 -> Vp fp16 pi-permuted transposed image (linear, no swizzle):
//   chunk (d', u=4*kc+g) at byte bt*8192 + d'*128 + u*16
//   content = {V[32kc+4g+r][d']}_{r=0..3} ++ {V[32kc+16+4g+r][d']}_{r=0..3}
__global__ __launch_bounds__(256)
void convert_kv_kernel(const float* __restrict__ Kg, const float* __restrict__ Vg,
                       _Float16* __restrict__ Kh, _Float16* __restrict__ Vp)
{
    __shared__ _Float16 tile[KVBLK * TSTR];
    const int bid = blockIdx.x;
    const int tid = threadIdx.x;
    if (bid < 1024) {
        const size_t base = ((size_t)bid * 256 + tid) * 8;
        f32x4 f0 = *(const f32x4*)(Kg + base);
        f32x4 f1 = *(const f32x4*)(Kg + base + 4);
        half8 h;
#pragma unroll
        for (int j = 0; j < 4; ++j) { h[j] = (_Float16)f0[j]; h[j+4] = (_Float16)f1[j]; }
        *(half8*)(Kh + base) = h;
    } else {
        const int bt = bid - 1024;               // bh*32 + t
        const int bh = bt >> 5, t = bt & 31;
        {
            const int kv = tid >> 2;
            const int d0 = (tid & 3) * 16;
            const float* src = Vg + ((size_t)bh * S_LEN + t * KVBLK + kv) * HDIM + d0;
            f32x4 f0 = *(const f32x4*)(src);
            f32x4 f1 = *(const f32x4*)(src + 4);
            f32x4 f2 = *(const f32x4*)(src + 8);
            f32x4 f3 = *(const f32x4*)(src + 12);
            half8 h0, h1;
#pragma unroll
            for (int j = 0; j < 4; ++j) {
                h0[j] = (_Float16)f0[j]; h0[j+4] = (_Float16)f1[j];
                h1[j] = (_Float16)f2[j]; h1[j+4] = (_Float16)f3[j];
            }
            *(half8*)&tile[kv * TSTR + d0]     = h0;
            *(half8*)&tile[kv * TSTR + d0 + 8] = h1;
        }
        __syncthreads();
        {
            const int dp = tid >> 2;             // d' = 0..63
            const int u0 = (tid & 3) * 2;
            char* base = (char*)Vp + (size_t)bt * 8192;
#pragma unroll
            for (int ui = 0; ui < 2; ++ui) {
                const int u  = u0 + ui;
                const int kc = u >> 2, gg = u & 3;
                half8 ch;
#pragma unroll
                for (int r = 0; r < 4; ++r) {
                    ch[r]     = tile[(32*kc + 4*gg + r)      * TSTR + dp];
                    ch[4 + r] = tile[(32*kc + 16 + 4*gg + r) * TSTR + dp];
                }
                *(half8*)(base + dp * 128 + u * 16) = ch;
            }
        }
    }
}

// ---- main attention kernel (v4: barrier-free, reg-staged K/V) ----------------------
__global__ __launch_bounds__(256, 3)
void relattn_v4(const float* __restrict__ Qg, const float* __restrict__ RELg,
                const _Float16* __restrict__ Kh, const _Float16* __restrict__ Vp,
                float* __restrict__ Og)
{
    __shared__ __attribute__((aligned(16))) _Float16 Qrel[QBLK * QRS]; // 33 KB only

    const int tid  = threadIdx.x;
    const int wave = tid >> 6;
    const int lane = tid & 63;
    const int c = lane & 15;
    const int g = lane >> 4;

    const int wk = ((blockIdx.x & 7) << 6) + (blockIdx.x >> 3);  // XCD-chunked, 512%8==0
    const int bh = wk >> 5;
    const int q0 = (wk & 31) * QBLK;

    const size_t hoff = (size_t)bh * S_LEN * HDIM;

    // ---- Q fragment (x0.125): lane holds Q[qg_][kc*32 + g*8 + j] ----
    const int qg_ = q0 + wave * 16 + c;
    half8 aq[2];
#pragma unroll
    for (int kc = 0; kc < 2; ++kc) {
        const float* src = Qg + hoff + (size_t)qg_ * HDIM + kc * 32 + g * 8;
        f32x4 f0 = *(const f32x4*)(src);
        f32x4 f1 = *(const f32x4*)(src + 4);
        half8 h;
#pragma unroll
        for (int j = 0; j < 4; ++j) {
            h[j]     = (_Float16)(f0[j] * 0.125f);
            h[j + 4] = (_Float16)(f1[j] * 0.125f);
        }
        aq[kc] = h;
    }

    // ---- qrel = (Q/8) @ rel_table^T via MFMA, rows owned per wave ----
#pragma unroll 1
    for (int t = 0; t < 17; ++t) {
        f32x4 acc = {0.f, 0.f, 0.f, 0.f};
        int r = t * 16 + c;
        if (r > 256) r = 256;
#pragma unroll
        for (int kc = 0; kc < 2; ++kc) {
            const float* src = RELg + (size_t)r * HDIM + kc * 32 + g * 8;
            f32x4 f0 = *(const f32x4*)(src);
            f32x4 f1 = *(const f32x4*)(src + 4);
            half8 b;
#pragma unroll
            for (int j = 0; j < 4; ++j) { b[j] = (_Float16)f0[j]; b[j+4] = (_Float16)f1[j]; }
            acc = __builtin_amdgcn_mfma_f32_16x16x32_f16(aq[kc], b, acc, 0, 0, 0);
        }
        const int col = t * 16 + c;
        if (col <= 256) {
#pragma unroll
            for (int reg = 0; reg < 4; ++reg)
                Qrel[(wave * 16 + 4 * g + reg) * QRS + col] = (_Float16)acc[reg];
        }
    }
    asm volatile("s_waitcnt lgkmcnt(0)" ::: "memory");   // own-wave qrel stores visible
    const _Float16* qr = &Qrel[(wave * 16 + c) * QRS];
    const float bias_lo = (float)qr[0];
    const float bias_hi = (float)qr[256];

    half8 ones;
#pragma unroll
    for (int j = 0; j < 8; ++j) ones[j] = (_Float16)1.0f;

    float m = -1e30f;
    f32x4 l_acc = {0.f, 0.f, 0.f, 0.f};
    f32x4 oacc[4];
#pragma unroll
    for (int i = 0; i < 4; ++i) oacc[i] = (f32x4){0.f, 0.f, 0.f, 0.f};

    // per-lane fragment byte offset within a tile image (identical for K and Vp):
    //   K  chunk (kc,n):  (16n+c)*128 + kc*64 + g*16
    //   Vp chunk (kc,dn): (16dn+c)*128 + kc*64 + g*16
    const int lk = c * 128 + g * 16;
    const char* kT = (const char*)Kh + (size_t)bh * NT * 8192 + lk;
    const char* vT = (const char*)Vp + (size_t)bh * NT * 8192 + lk;

    half8 kr[2][4], vr[2][4];
#pragma unroll
    for (int kc = 0; kc < 2; ++kc)
#pragma unroll
        for (int n = 0; n < 4; ++n)
            kr[kc][n] = *(const half8*)(kT + n * 2048 + kc * 64);
#pragma unroll
    for (int kc = 0; kc < 2; ++kc)
#pragma unroll
        for (int dn = 0; dn < 4; ++dn)
            vr[kc][dn] = *(const half8*)(vT + dn * 2048 + kc * 64);

#pragma unroll 1
    for (int t = 0; t < NT; ++t) {
        const int k0 = t * KVBLK;

        // ---- S^T = K @ Q^T : sacc[n][r] = S[kv=16n+4g+r][q=c] ----
        f32x4 sacc[4];
#pragma unroll
        for (int n = 0; n < 4; ++n) sacc[n] = (f32x4){0.f,0.f,0.f,0.f};
        __builtin_amdgcn_s_setprio(1);
#pragma unroll
        for (int n = 0; n < 4; ++n)
            sacc[n] = __builtin_amdgcn_mfma_f32_16x16x32_f16(kr[0][n], aq[0], sacc[n], 0, 0, 0);
#pragma unroll
        for (int n = 0; n < 4; ++n)
            sacc[n] = __builtin_amdgcn_mfma_f32_16x16x32_f16(kr[1][n], aq[1], sacc[n], 0, 0, 0);
        __builtin_amdgcn_s_setprio(0);

        // ---- prefetch next K tile (single-set: issue right after last QK use) ----
        const char* kTn = kT + ((t + 1 < NT) ? 8192 : 0);
#pragma unroll
        for (int kc = 0; kc < 2; ++kc)
#pragma unroll
            for (int n = 0; n < 4; ++n)
                kr[kc][n] = *(const half8*)(kTn + n * 2048 + kc * 64);
        kT = kTn;

        // ---- bias + online softmax ----
        const bool band = (k0 + 192 > q0) && (k0 < q0 + 192);
        float fold, mtb;
        if (!band) {
            const float bc = (k0 < q0) ? bias_lo : bias_hi;
            float mt = sacc[0][0];
#pragma unroll
            for (int n = 0; n < 4; ++n)
#pragma unroll
                for (int r = 0; r < 4; ++r) mt = fmaxf(mt, sacc[n][r]);
            mt = fmaxf(mt, __shfl_xor(mt, 16, 64));
            mt = fmaxf(mt, __shfl_xor(mt, 32, 64));
            mtb = mt + bc;
            if (!__all(mtb <= m + 8.f)) {
                const float mnew = fmaxf(m, mtb);
                const float al = __builtin_amdgcn_exp2f((m - mnew) * L2E);
                m = mnew;
#pragma unroll
                for (int r = 0; r < 4; ++r) {
                    const float ar = __shfl(al, 20 * g + r, 64);
                    l_acc[r] *= ar;
#pragma unroll
                    for (int dn = 0; dn < 4; ++dn) oacc[dn][r] *= ar;
                }
            }
            fold = (bc - m) * L2E;
        } else {
            const int base_d = k0 + 4 * g - qg_ + 128;
            float mt = -1e30f;
#pragma unroll
            for (int n = 0; n < 4; ++n) {
#pragma unroll
                for (int r = 0; r < 4; ++r) {
                    int idx = base_d + 16 * n + r;
                    idx = idx < 0 ? 0 : (idx > 256 ? 256 : idx);
                    sacc[n][r] += (float)qr[idx];
                    mt = fmaxf(mt, sacc[n][r]);
                }
            }
            mt = fmaxf(mt, __shfl_xor(mt, 16, 64));
            mt = fmaxf(mt, __shfl_xor(mt, 32, 64));
            mtb = mt;
            if (!__all(mtb <= m + 8.f)) {
                const float mnew = fmaxf(m, mtb);
                const float al = __builtin_amdgcn_exp2f((m - mnew) * L2E);
                m = mnew;
#pragma unroll
                for (int r = 0; r < 4; ++r) {
                    const float ar = __shfl(al, 20 * g + r, 64);
                    l_acc[r] *= ar;
#pragma unroll
                    for (int dn = 0; dn < 4; ++dn) oacc[dn][r] *= ar;
                }
            }
            fold = -m * L2E;
        }

        // ---- P = exp2(S*log2e + fold), packed straight into A-fragments ----
        half4 p4[4];
#pragma unroll
        for (int n = 0; n < 4; ++n) {
#pragma unroll
            for (int r = 0; r < 4; ++r) {
                const float pv = __builtin_amdgcn_exp2f(fmaf(sacc[n][r], L2E, fold));
                p4[n][r] = (_Float16)pv;
            }
        }
        half8 ap0, ap1;
#pragma unroll
        for (int r = 0; r < 4; ++r) {
            ap0[r] = p4[0][r]; ap0[4 + r] = p4[1][r];
            ap1[r] = p4[2][r]; ap1[4 + r] = p4[3][r];
        }

        // ---- O += P @ V ; l += P @ 1 ----
        __builtin_amdgcn_s_setprio(1);
        l_acc = __builtin_amdgcn_mfma_f32_16x16x32_f16(ap0, ones, l_acc, 0, 0, 0);
        l_acc = __builtin_amdgcn_mfma_f32_16x16x32_f16(ap1, ones, l_acc, 0, 0, 0);
#pragma unroll
        for (int dn = 0; dn < 4; ++dn)
            oacc[dn] = __builtin_amdgcn_mfma_f32_16x16x32_f16(ap0, vr[0][dn], oacc[dn], 0, 0, 0);
#pragma unroll
        for (int dn = 0; dn < 4; ++dn)
            oacc[dn] = __builtin_amdgcn_mfma_f32_16x16x32_f16(ap1, vr[1][dn], oacc[dn], 0, 0, 0);
        __builtin_amdgcn_s_setprio(0);

        // ---- prefetch next V tile ----
        const char* vTn = vT + ((t + 1 < NT) ? 8192 : 0);
#pragma unroll
        for (int kc = 0; kc < 2; ++kc)
#pragma unroll
            for (int dn = 0; dn < 4; ++dn)
                vr[kc][dn] = *(const half8*)(vTn + dn * 2048 + kc * 64);
        vT = vTn;
    }

    // ---- epilogue: O[q=wave*16+4g+r... wait layout: row q = c? No: dst row uses 4g+r ----
#pragma unroll
    for (int r = 0; r < 4; ++r) {
        const float inv = 1.0f / l_acc[r];
        float* dst = Og + hoff + (size_t)(q0 + wave * 16 + 4 * g + r) * HDIM + c;
#pragma unroll
        for (int dn = 0; dn < 4; ++dn)
            dst[16 * dn] = oacc[dn][r] * inv;
    }
}

// ---- fallback (round-1 kernel, used if ws too small) --------------------------------
__global__ __launch_bounds__(256, 2)
void relattn_v1(const float* __restrict__ Qg, const float* __restrict__ Kg,
                const float* __restrict__ Vg, const float* __restrict__ RELg,
                float* __restrict__ Og)
{
    __shared__ _Float16 Klds[KVBLK * HDIM];
    __shared__ _Float16 Vt[HDIM * KVBLK];
    __shared__ _Float16 Plds[4][16 * KVBLK];
    __shared__ _Float16 Qrel[QBLK * QRS];

    const int tid  = threadIdx.x;
    const int wave = tid >> 6;
    const int lane = tid & 63;
    const int c = lane & 15;
    const int g = lane >> 4;

    const int bid = blockIdx.x;
    const int bh  = bid >> 5;
    const int q0  = (bid & 31) * QBLK;

    const size_t hoff = (size_t)bh * S_LEN * HDIM;
    const float* Qh = Qg + hoff;
    const float* Kh = Kg + hoff;
    const float* Vh = Vg + hoff;

    const int qrow_frag = q0 + wave * 16 + c;
    half8 aq[2];
#pragma unroll
    for (int kc = 0; kc < 2; ++kc) {
        const float* src = Qh + (size_t)qrow_frag * HDIM + kc * 32 + g * 8;
        f32x4 f0 = *(const f32x4*)(src);
        f32x4 f1 = *(const f32x4*)(src + 4);
        half8 h;
#pragma unroll
        for (int j = 0; j < 4; ++j) {
            h[j]     = (_Float16)(f0[j] * 0.125f);
            h[j + 4] = (_Float16)(f1[j] * 0.125f);
        }
        aq[kc] = h;
    }

#pragma unroll 1
    for (int t = 0; t < 17; ++t) {
        f32x4 acc = {0.f, 0.f, 0.f, 0.f};
        int r = t * 16 + c;
        if (r > 256) r = 256;
#pragma unroll
        for (int kc = 0; kc < 2; ++kc) {
            const float* src = RELg + (size_t)r * HDIM + kc * 32 + g * 8;
            f32x4 f0 = *(const f32x4*)(src);
            f32x4 f1 = *(const f32x4*)(src + 4);
            half8 b;
#pragma unroll
            for (int j = 0; j < 4; ++j) { b[j] = (_Float16)f0[j]; b[j+4] = (_Float16)f1[j]; }
            acc = __builtin_amdgcn_mfma_f32_16x16x32_f16(aq[kc], b, acc, 0, 0, 0);
        }
        const int col = t * 16 + c;
        if (col <= 256) {
#pragma unroll
            for (int reg = 0; reg < 4; ++reg)
                Qrel[(wave * 16 + 4 * g + reg) * QRS + col] = (_Float16)acc[reg];
        }
    }

    float mrow[4], lrow[4];
    f32x4 oacc[4];
#pragma unroll
    for (int i = 0; i < 4; ++i) {
        mrow[i] = -1e30f; lrow[i] = 0.f;
        oacc[i] = (f32x4){0.f, 0.f, 0.f, 0.f};
    }

    for (int k0 = 0; k0 < S_LEN; k0 += KVBLK) {
        __syncthreads();
        {
            const int r  = tid >> 2;
            const int dq = (tid & 3) << 4;
            const float* src = Kh + (size_t)(k0 + r) * HDIM + dq;
            f32x4 f0 = *(const f32x4*)(src);
            f32x4 f1 = *(const f32x4*)(src + 4);
            f32x4 f2 = *(const f32x4*)(src + 8);
            f32x4 f3 = *(const f32x4*)(src + 12);
            half8 h0, h1;
#pragma unroll
            for (int j = 0; j < 4; ++j) {
                h0[j] = (_Float16)f0[j]; h0[j+4] = (_Float16)f1[j];
                h1[j] = (_Float16)f2[j]; h1[j+4] = (_Float16)f3[j];
            }
            const int swz = (r & 7) << 4;
            char* base = (char*)Klds;
            *(half8*)(base + ((r * 128 + dq * 2) ^ swz))      = h0;
            *(half8*)(base + ((r * 128 + dq * 2 + 16) ^ swz)) = h1;
        }
        {
            const int kv = tid & 63;
            const int dbase = (tid >> 6) << 4;
            const float* src = Vh + (size_t)(k0 + kv) * HDIM + dbase;
            f32x4 f0 = *(const f32x4*)(src);
            f32x4 f1 = *(const f32x4*)(src + 4);
            f32x4 f2 = *(const f32x4*)(src + 8);
            f32x4 f3 = *(const f32x4*)(src + 12);
            float vals[16];
#pragma unroll
            for (int j = 0; j < 4; ++j) {
                vals[j] = f0[j]; vals[4+j] = f1[j]; vals[8+j] = f2[j]; vals[12+j] = f3[j];
            }
            char* base = (char*)Vt;
#pragma unroll
            for (int i = 0; i < 16; ++i) {
                const int d = dbase + i;
                const int off = (d * 128 + kv * 2) ^ ((d & 7) << 4);
                *(_Float16*)(base + off) = (_Float16)vals[i];
            }
        }
        __syncthreads();

        f32x4 sacc[4];
#pragma unroll
        for (int n = 0; n < 4; ++n) sacc[n] = (f32x4){0.f,0.f,0.f,0.f};
#pragma unroll
        for (int kc = 0; kc < 2; ++kc) {
#pragma unroll
            for (int n = 0; n < 4; ++n) {
                const int off = (((16*n + c) * 128) + kc * 64 + g * 16) ^ ((c & 7) << 4);
                half8 bk = *(const half8*)((const char*)Klds + off);
                sacc[n] = __builtin_amdgcn_mfma_f32_16x16x32_f16(aq[kc], bk, sacc[n], 0, 0, 0);
            }
        }

        float sval[4][4];
        const int myq0 = q0 + wave * 16 + 4 * g;
#pragma unroll
        for (int n = 0; n < 4; ++n) {
            const int kpos = k0 + 16 * n + c;
#pragma unroll
            for (int reg = 0; reg < 4; ++reg) {
                int rel = kpos - (myq0 + reg);
                rel = rel < -128 ? -128 : (rel > 128 ? 128 : rel);
                const float bias = (float)Qrel[(wave*16 + 4*g + reg) * QRS + (rel + 128)];
                sval[n][reg] = sacc[n][reg] + bias;
            }
        }

        float mt[4];
#pragma unroll
        for (int reg = 0; reg < 4; ++reg) {
            float mp = fmaxf(fmaxf(sval[0][reg], sval[1][reg]),
                             fmaxf(sval[2][reg], sval[3][reg]));
#pragma unroll
            for (int msk = 1; msk < 16; msk <<= 1)
                mp = fmaxf(mp, __shfl_xor(mp, msk, 64));
            mt[reg] = mp;
        }

        float alpha[4], psum[4];
#pragma unroll
        for (int reg = 0; reg < 4; ++reg) {
            const float mn = fmaxf(mrow[reg], mt[reg]);
            alpha[reg] = __expf(mrow[reg] - mn);
            mrow[reg] = mn;
            psum[reg] = 0.f;
        }

        char* pbase = (char*)&Plds[wave][0];
#pragma unroll
        for (int n = 0; n < 4; ++n) {
#pragma unroll
            for (int reg = 0; reg < 4; ++reg) {
                const float pv = __expf(sval[n][reg] - mrow[reg]);
                psum[reg] += pv;
                const int row = 4 * g + reg;
                const int off = (row * 128 + (16 * n + c) * 2) ^ ((row & 7) << 4);
                *(_Float16*)(pbase + off) = (_Float16)pv;
            }
        }

#pragma unroll
        for (int reg = 0; reg < 4; ++reg) {
            float ps = psum[reg];
#pragma unroll
            for (int msk = 1; msk < 16; msk <<= 1)
                ps += __shfl_xor(ps, msk, 64);
            lrow[reg] = lrow[reg] * alpha[reg] + ps;
#pragma unroll
            for (int dn = 0; dn < 4; ++dn) oacc[dn][reg] *= alpha[reg];
        }

        asm volatile("s_waitcnt lgkmcnt(0)" ::: "memory");

        half8 ap[2];
#pragma unroll
        for (int kc = 0; kc < 2; ++kc) {
            const int off = (c * 128 + kc * 64 + g * 16) ^ ((c & 7) << 4);
            ap[kc] = *(const half8*)(pbase + off);
        }
#pragma unroll
        for (int kc = 0; kc < 2; ++kc) {
#pragma unroll
            for (int dn = 0; dn < 4; ++dn) {
                const int drow = 16 * dn + c;
                const int off = (drow * 128 + kc * 64 + g * 16) ^ ((c & 7) << 4);
                half8 bv = *(const half8*)((const char*)Vt + off);
                oacc[dn] = __builtin_amdgcn_mfma_f32_16x16x32_f16(ap[kc], bv, oacc[dn], 0, 0, 0);
            }
        }
    }

#pragma unroll
    for (int reg = 0; reg < 4; ++reg) {
        const float inv = 1.0f / lrow[reg];
        const int row = q0 + wave * 16 + 4 * g + reg;
        float* dst = Og + hoff + (size_t)row * HDIM + c;
#pragma unroll
        for (int dn = 0; dn < 4; ++dn)
            dst[16 * dn] = oacc[dn][reg] * inv;
    }
}

extern "C" void kernel_launch(void* const* d_in, const int* in_sizes, int n_in,
                              void* d_out, int out_size, void* d_ws, size_t ws_size,
                              hipStream_t stream) {
    const float* q   = (const float*)d_in[0];
    const float* k   = (const float*)d_in[1];
    const float* v   = (const float*)d_in[2];
    const float* rel = (const float*)d_in[3];
    float* out = (float*)d_out;
    (void)in_sizes; (void)n_in; (void)out_size;

    const size_t kv_bytes = (size_t)NBH * S_LEN * HDIM * sizeof(_Float16);  // 4 MB each
    if (ws_size >= 2 * kv_bytes) {
        _Float16* KhB = (_Float16*)d_ws;
        _Float16* VpB = (_Float16*)((char*)d_ws + kv_bytes);
        convert_kv_kernel<<<dim3(1536), 256, 0, stream>>>(k, v, KhB, VpB);
        relattn_v4<<<dim3(NBH * (S_LEN / QBLK)), 256, 0, stream>>>(q, rel, KhB, VpB, out);
    } else {
        relattn_v1<<<dim3(NBH * (S_LEN / QBLK)), 256, 0, stream>>>(q, k, v, rel, out);
    }
}

// Round 5
// 137.084 us; speedup vs baseline: 1.0377x; 1.0377x over previous
//
#include <hip/hip_runtime.h>

typedef _Float16 half8 __attribute__((ext_vector_type(8)));
typedef _Float16 half4 __attribute__((ext_vector_type(4)));
typedef float f32x4 __attribute__((ext_vector_type(4)));

#define S_LEN 2048
#define HDIM 64
#define QBLK 64
#define KVBLK 64
#define NT (S_LEN / KVBLK)
#define NHALF 16          // tiles per kv-half
#define QRS 258
#define NBH 16
#define L2E 1.44269504f
#define TSTR 72

__device__ __forceinline__ void load_lds16(const void* g, void* l) {
    __builtin_amdgcn_global_load_lds(
        (const __attribute__((address_space(1))) unsigned int*)g,
        (__attribute__((address_space(3))) unsigned int*)l, 16, 0, 0);
}

// ---- fused pre-pass ----------------------------------------------------------------
// blocks 0..1023: K fp32 -> Kh fp16 per-tile swizzled LDS image:
//   (bh,t,kv,d) at byte (bh*32+t)*8192 + ((kv*128 + d*2) ^ ((kv&7)<<4))
// blocks 1024..1535: V fp32 -> Vp fp16 pi-permuted transposed image (linear):
//   chunk (d', u=4*kc+g) at byte bt*8192 + d'*128 + u*16
__global__ __launch_bounds__(256)
void convert_kv_kernel(const float* __restrict__ Kg, const float* __restrict__ Vg,
                       _Float16* __restrict__ Kh, _Float16* __restrict__ Vp)
{
    __shared__ _Float16 tile[KVBLK * TSTR];
    const int bid = blockIdx.x;
    const int tid = threadIdx.x;
    if (bid < 1024) {
        const int id = bid * 256 + tid;
        const int r  = id >> 3;
        const int d0 = (id & 7) * 8;
        const float* src = Kg + (size_t)r * HDIM + d0;
        f32x4 f0 = *(const f32x4*)(src);
        f32x4 f1 = *(const f32x4*)(src + 4);
        half8 h;
#pragma unroll
        for (int j = 0; j < 4; ++j) { h[j] = (_Float16)f0[j]; h[j+4] = (_Float16)f1[j]; }
        const int bh = r >> 11, kvg = r & 2047;
        const int t = kvg >> 6, kv = kvg & 63;
        const size_t blk = (size_t)(bh * NT + t) * 8192;
        const int off = (kv * 128 + d0 * 2) ^ ((kv & 7) << 4);
        *(half8*)((char*)Kh + blk + off) = h;
    } else {
        const int bt = bid - 1024;               // bh*32 + t
        const int bh = bt >> 5, t = bt & 31;
        {
            const int kv = tid >> 2;
            const int d0 = (tid & 3) * 16;
            const float* src = Vg + ((size_t)bh * S_LEN + t * KVBLK + kv) * HDIM + d0;
            f32x4 f0 = *(const f32x4*)(src);
            f32x4 f1 = *(const f32x4*)(src + 4);
            f32x4 f2 = *(const f32x4*)(src + 8);
            f32x4 f3 = *(const f32x4*)(src + 12);
            half8 h0, h1;
#pragma unroll
            for (int j = 0; j < 4; ++j) {
                h0[j] = (_Float16)f0[j]; h0[j+4] = (_Float16)f1[j];
                h1[j] = (_Float16)f2[j]; h1[j+4] = (_Float16)f3[j];
            }
            *(half8*)&tile[kv * TSTR + d0]     = h0;
            *(half8*)&tile[kv * TSTR + d0 + 8] = h1;
        }
        __syncthreads();
        {
            const int dp = tid >> 2;
            const int u0 = (tid & 3) * 2;
            char* base = (char*)Vp + (size_t)bt * 8192;
#pragma unroll
            for (int ui = 0; ui < 2; ++ui) {
                const int u  = u0 + ui;
                const int kc = u >> 2, gg = u & 3;
                half8 ch;
#pragma unroll
                for (int r = 0; r < 4; ++r) {
                    ch[r]     = tile[(32*kc + 4*gg + r)      * TSTR + dp];
                    ch[4 + r] = tile[(32*kc + 16 + 4*gg + r) * TSTR + dp];
                }
                *(half8*)(base + dp * 128 + u * 16) = ch;
            }
        }
    }
}

// ---- main attention kernel (v5: KV-split-2, K->LDS dbuf, V->regs, partial out) -----
__global__ __launch_bounds__(256, 3)
void relattn_v5(const float* __restrict__ Qg, const float* __restrict__ RELg,
                const _Float16* __restrict__ Kh, const _Float16* __restrict__ Vp,
                _Float16* __restrict__ Opart, float* __restrict__ Mpart,
                float* __restrict__ Lpart)
{
    __shared__ __attribute__((aligned(16))) _Float16 Kbuf[2][4096];    // 16 KB
    __shared__ __attribute__((aligned(16))) _Float16 Qrel[QBLK * QRS]; // 33 KB

    const int tid  = threadIdx.x;
    const int wave = tid >> 6;
    const int lane = tid & 63;
    const int c = lane & 15;
    const int g = lane >> 4;

    // XCD-chunked swizzle over 1024 blocks (1024 % 8 == 0 -> bijective)
    const int wk = ((blockIdx.x & 7) << 7) + (blockIdx.x >> 3);
    const int qb = wk >> 1;        // 0..511 : q-tile id
    const int hv = wk & 1;         // kv half
    const int bh = qb >> 5;
    const int q0 = (qb & 31) * QBLK;
    const int wk_l = qb * 2 + hv;  // logical partial index

    const size_t hoff = (size_t)bh * S_LEN * HDIM;

    // ---- Q fragment (x0.125) ----
    const int qg_ = q0 + wave * 16 + c;
    half8 aq[2];
#pragma unroll
    for (int kc = 0; kc < 2; ++kc) {
        const float* src = Qg + hoff + (size_t)qg_ * HDIM + kc * 32 + g * 8;
        f32x4 f0 = *(const f32x4*)(src);
        f32x4 f1 = *(const f32x4*)(src + 4);
        half8 h;
#pragma unroll
        for (int j = 0; j < 4; ++j) {
            h[j]     = (_Float16)(f0[j] * 0.125f);
            h[j + 4] = (_Float16)(f1[j] * 0.125f);
        }
        aq[kc] = h;
    }

    // ---- qrel = (Q/8) @ rel_table^T via MFMA ----
#pragma unroll 1
    for (int t = 0; t < 17; ++t) {
        f32x4 acc = {0.f, 0.f, 0.f, 0.f};
        int r = t * 16 + c;
        if (r > 256) r = 256;
#pragma unroll
        for (int kc = 0; kc < 2; ++kc) {
            const float* src = RELg + (size_t)r * HDIM + kc * 32 + g * 8;
            f32x4 f0 = *(const f32x4*)(src);
            f32x4 f1 = *(const f32x4*)(src + 4);
            half8 b;
#pragma unroll
            for (int j = 0; j < 4; ++j) { b[j] = (_Float16)f0[j]; b[j+4] = (_Float16)f1[j]; }
            acc = __builtin_amdgcn_mfma_f32_16x16x32_f16(aq[kc], b, acc, 0, 0, 0);
        }
        const int col = t * 16 + c;
        if (col <= 256) {
#pragma unroll
            for (int reg = 0; reg < 4; ++reg)
                Qrel[(wave * 16 + 4 * g + reg) * QRS + col] = (_Float16)acc[reg];
        }
    }
    asm volatile("s_waitcnt lgkmcnt(0)" ::: "memory");
    const _Float16* qr = &Qrel[(wave * 16 + c) * QRS];
    const float bias_lo = (float)qr[0];
    const float bias_hi = (float)qr[256];

    half8 ones;
#pragma unroll
    for (int j = 0; j < 8; ++j) ones[j] = (_Float16)1.0f;

    float m = -1e30f;
    f32x4 l_acc = {0.f, 0.f, 0.f, 0.f};
    f32x4 oacc[4];
#pragma unroll
    for (int i = 0; i < 4; ++i) oacc[i] = (f32x4){0.f, 0.f, 0.f, 0.f};

    const char* kbase = (const char*)Kh + (size_t)bh * NT * 8192;
    const int lk = c * 128 + g * 16;
    const char* vT = (const char*)Vp + (size_t)bh * NT * 8192 + lk;
    const int goff = wave * 2048 + lane * 16;
    const int loff = wave * 2048;
    const int tstart = hv * NHALF;
    const int tend   = tstart + NHALF;

#define ISSUE_K(tt, bb) do {                                            \
        const char* kt = kbase + (size_t)(tt) * 8192 + goff;            \
        char* kl = (char*)Kbuf + (bb) * 8192 + loff;                    \
        load_lds16(kt,        kl);                                      \
        load_lds16(kt + 1024, kl + 1024);                               \
    } while (0)

#define LOADV(dst, tt) do {                                             \
        const char* vt_ = vT + (size_t)(tt) * 8192;                     \
        _Pragma("unroll")                                               \
        for (int kc = 0; kc < 2; ++kc)                                  \
            _Pragma("unroll")                                           \
            for (int dn = 0; dn < 4; ++dn)                              \
                dst[kc][dn] = *(const half8*)(vt_ + dn * 2048 + kc * 64); \
    } while (0)

#define BODY(t, b, VC, VN) do {                                                      \
        const int tn = ((t) + 1 < tend) ? (t) + 1 : (t);                             \
        ISSUE_K(tn, (b) ^ 1);                                                        \
        asm volatile("s_waitcnt vmcnt(10)" ::: "memory");                            \
        __builtin_amdgcn_s_barrier();                                                \
        const int k0 = (t) * KVBLK;                                                  \
        f32x4 sacc[4];                                                               \
        _Pragma("unroll")                                                            \
        for (int n = 0; n < 4; ++n) sacc[n] = (f32x4){0.f,0.f,0.f,0.f};              \
        __builtin_amdgcn_s_setprio(1);                                               \
        _Pragma("unroll")                                                            \
        for (int n = 0; n < 4; ++n) {                                                \
            half8 ak0 = *(const half8*)((const char*)Kbuf + (b)*8192 + c*128 + (g*16 ^ ((c&7)<<4)) + n*2048); \
            sacc[n] = __builtin_amdgcn_mfma_f32_16x16x32_f16(ak0, aq[0], sacc[n], 0, 0, 0); \
        }                                                                            \
        _Pragma("unroll")                                                            \
        for (int n = 0; n < 4; ++n) {                                                \
            half8 ak1 = *(const half8*)((const char*)Kbuf + (b)*8192 + c*128 + ((64 + g*16) ^ ((c&7)<<4)) + n*2048); \
            sacc[n] = __builtin_amdgcn_mfma_f32_16x16x32_f16(ak1, aq[1], sacc[n], 0, 0, 0); \
        }                                                                            \
        __builtin_amdgcn_s_setprio(0);                                               \
        LOADV(VN, tn);                                                               \
        const bool band = (k0 + 192 > q0) && (k0 < q0 + 192);                        \
        float fold, mtb;                                                             \
        if (!band) {                                                                 \
            const float bc = (k0 < q0) ? bias_lo : bias_hi;                          \
            float mt = sacc[0][0];                                                   \
            _Pragma("unroll")                                                        \
            for (int n = 0; n < 4; ++n)                                              \
                _Pragma("unroll")                                                    \
                for (int r = 0; r < 4; ++r) mt = fmaxf(mt, sacc[n][r]);              \
            mt = fmaxf(mt, __shfl_xor(mt, 16, 64));                                  \
            mt = fmaxf(mt, __shfl_xor(mt, 32, 64));                                  \
            mtb = mt + bc;                                                           \
            if (!__all(mtb <= m + 8.f)) {                                            \
                const float mnew = fmaxf(m, mtb);                                    \
                const float al = __builtin_amdgcn_exp2f((m - mnew) * L2E);           \
                m = mnew;                                                            \
                _Pragma("unroll")                                                    \
                for (int r = 0; r < 4; ++r) {                                        \
                    const float ar = __shfl(al, 20 * g + r, 64);                     \
                    l_acc[r] *= ar;                                                  \
                    _Pragma("unroll")                                                \
                    for (int dn = 0; dn < 4; ++dn) oacc[dn][r] *= ar;                \
                }                                                                    \
            }                                                                        \
            fold = (bc - m) * L2E;                                                   \
        } else {                                                                     \
            const int base_d = k0 + 4 * g - qg_ + 128;                               \
            float mt = -1e30f;                                                       \
            _Pragma("unroll")                                                        \
            for (int n = 0; n < 4; ++n) {                                            \
                _Pragma("unroll")                                                    \
                for (int r = 0; r < 4; ++r) {                                        \
                    int idx = base_d + 16 * n + r;                                   \
                    idx = idx < 0 ? 0 : (idx > 256 ? 256 : idx);                     \
                    sacc[n][r] += (float)qr[idx];                                    \
                    mt = fmaxf(mt, sacc[n][r]);                                      \
                }                                                                    \
            }                                                                        \
            mt = fmaxf(mt, __shfl_xor(mt, 16, 64));                                  \
            mt = fmaxf(mt, __shfl_xor(mt, 32, 64));                                  \
            mtb = mt;                                                                \
            if (!__all(mtb <= m + 8.f)) {                                            \
                const float mnew = fmaxf(m, mtb);                                    \
                const float al = __builtin_amdgcn_exp2f((m - mnew) * L2E);           \
                m = mnew;                                                            \
                _Pragma("unroll")                                                    \
                for (int r = 0; r < 4; ++r) {                                        \
                    const float ar = __shfl(al, 20 * g + r, 64);                     \
                    l_acc[r] *= ar;                                                  \
                    _Pragma("unroll")                                                \
                    for (int dn = 0; dn < 4; ++dn) oacc[dn][r] *= ar;                \
                }                                                                    \
            }                                                                        \
            fold = -m * L2E;                                                         \
        }                                                                            \
        half4 p4[4];                                                                 \
        _Pragma("unroll")                                                            \
        for (int n = 0; n < 4; ++n) {                                                \
            _Pragma("unroll")                                                        \
            for (int r = 0; r < 4; ++r) {                                            \
                const float pv = __builtin_amdgcn_exp2f(fmaf(sacc[n][r], L2E, fold));\
                p4[n][r] = (_Float16)pv;                                             \
            }                                                                        \
        }                                                                            \
        half8 ap0, ap1;                                                              \
        _Pragma("unroll")                                                            \
        for (int r = 0; r < 4; ++r) {                                                \
            ap0[r] = p4[0][r]; ap0[4 + r] = p4[1][r];                                \
            ap1[r] = p4[2][r]; ap1[4 + r] = p4[3][r];                                \
        }                                                                            \
        __builtin_amdgcn_s_setprio(1);                                               \
        l_acc = __builtin_amdgcn_mfma_f32_16x16x32_f16(ap0, ones, l_acc, 0, 0, 0);   \
        l_acc = __builtin_amdgcn_mfma_f32_16x16x32_f16(ap1, ones, l_acc, 0, 0, 0);   \
        _Pragma("unroll")                                                            \
        for (int dn = 0; dn < 4; ++dn)                                               \
            oacc[dn] = __builtin_amdgcn_mfma_f32_16x16x32_f16(ap0, VC[0][dn], oacc[dn], 0, 0, 0); \
        _Pragma("unroll")                                                            \
        for (int dn = 0; dn < 4; ++dn)                                               \
            oacc[dn] = __builtin_amdgcn_mfma_f32_16x16x32_f16(ap1, VC[1][dn], oacc[dn], 0, 0, 0); \
        __builtin_amdgcn_s_setprio(0);                                               \
        __builtin_amdgcn_s_barrier();                                                \
    } while (0)

    half8 va[2][4], vb[2][4];
    ISSUE_K(tstart, 0);
    LOADV(va, tstart);

#pragma unroll 1
    for (int i = 0; i < NHALF; i += 2) {
        BODY(tstart + i,     0, va, vb);
        BODY(tstart + i + 1, 1, vb, va);
    }
    asm volatile("s_waitcnt vmcnt(0)" ::: "memory");
#undef BODY
#undef LOADV
#undef ISSUE_K

    // ---- partial epilogue (unnormalized) ----
    {
        _Float16* od = Opart + (size_t)wk_l * 4096;
#pragma unroll
        for (int r = 0; r < 4; ++r) {
            const int row = wave * 16 + 4 * g + r;
#pragma unroll
            for (int dn = 0; dn < 4; ++dn)
                od[row * 64 + 16 * dn + c] = (_Float16)oacc[dn][r];
        }
        if (g == 0)
            Mpart[(size_t)wk_l * 64 + wave * 16 + c] = m;
        if (c == 0) {
#pragma unroll
            for (int r = 0; r < 4; ++r)
                Lpart[(size_t)wk_l * 64 + wave * 16 + 4 * g + r] = l_acc[r];
        }
    }
}

// ---- combine: out = (O0*w0 + O1*w1) / (l0*w0 + l1*w1) ------------------------------
__global__ __launch_bounds__(256)
void combine_kernel(const _Float16* __restrict__ Opart, const float* __restrict__ Mpart,
                    const float* __restrict__ Lpart, float* __restrict__ Og)
{
    const int tid = threadIdx.x;
    const int row = blockIdx.x * 16 + (tid >> 4);   // 0..32767 global q-row
    const int col = (tid & 15) * 4;
    const int qt  = (row >> 6);                     // bh*32 + q-tile
    const int r64 = row & 63;
    const int p0 = qt * 2, p1 = p0 + 1;

    const float m0 = Mpart[(size_t)p0 * 64 + r64];
    const float m1 = Mpart[(size_t)p1 * 64 + r64];
    const float l0 = Lpart[(size_t)p0 * 64 + r64];
    const float l1 = Lpart[(size_t)p1 * 64 + r64];
    const float M  = fmaxf(m0, m1);
    const float w0 = __builtin_amdgcn_exp2f((m0 - M) * L2E);
    const float w1 = __builtin_amdgcn_exp2f((m1 - M) * L2E);
    const float inv = 1.0f / (l0 * w0 + l1 * w1);

    const half4 o0 = *(const half4*)(Opart + (size_t)p0 * 4096 + r64 * 64 + col);
    const half4 o1 = *(const half4*)(Opart + (size_t)p1 * 4096 + r64 * 64 + col);
    f32x4 out;
#pragma unroll
    for (int j = 0; j < 4; ++j)
        out[j] = ((float)o0[j] * w0 + (float)o1[j] * w1) * inv;
    *(f32x4*)(Og + (size_t)row * 64 + col) = out;
}

// ---- fallback (round-1 kernel, used if ws too small) --------------------------------
__global__ __launch_bounds__(256, 2)
void relattn_v1(const float* __restrict__ Qg, const float* __restrict__ Kg,
                const float* __restrict__ Vg, const float* __restrict__ RELg,
                float* __restrict__ Og)
{
    __shared__ _Float16 Klds[KVBLK * HDIM];
    __shared__ _Float16 Vt[HDIM * KVBLK];
    __shared__ _Float16 Plds[4][16 * KVBLK];
    __shared__ _Float16 Qrel[QBLK * QRS];

    const int tid  = threadIdx.x;
    const int wave = tid >> 6;
    const int lane = tid & 63;
    const int c = lane & 15;
    const int g = lane >> 4;

    const int bid = blockIdx.x;
    const int bh  = bid >> 5;
    const int q0  = (bid & 31) * QBLK;

    const size_t hoff = (size_t)bh * S_LEN * HDIM;
    const float* Qh = Qg + hoff;
    const float* Kh = Kg + hoff;
    const float* Vh = Vg + hoff;

    const int qrow_frag = q0 + wave * 16 + c;
    half8 aq[2];
#pragma unroll
    for (int kc = 0; kc < 2; ++kc) {
        const float* src = Qh + (size_t)qrow_frag * HDIM + kc * 32 + g * 8;
        f32x4 f0 = *(const f32x4*)(src);
        f32x4 f1 = *(const f32x4*)(src + 4);
        half8 h;
#pragma unroll
        for (int j = 0; j < 4; ++j) {
            h[j]     = (_Float16)(f0[j] * 0.125f);
            h[j + 4] = (_Float16)(f1[j] * 0.125f);
        }
        aq[kc] = h;
    }

#pragma unroll 1
    for (int t = 0; t < 17; ++t) {
        f32x4 acc = {0.f, 0.f, 0.f, 0.f};
        int r = t * 16 + c;
        if (r > 256) r = 256;
#pragma unroll
        for (int kc = 0; kc < 2; ++kc) {
            const float* src = RELg + (size_t)r * HDIM + kc * 32 + g * 8;
            f32x4 f0 = *(const f32x4*)(src);
            f32x4 f1 = *(const f32x4*)(src + 4);
            half8 b;
#pragma unroll
            for (int j = 0; j < 4; ++j) { b[j] = (_Float16)f0[j]; b[j+4] = (_Float16)f1[j]; }
            acc = __builtin_amdgcn_mfma_f32_16x16x32_f16(aq[kc], b, acc, 0, 0, 0);
        }
        const int col = t * 16 + c;
        if (col <= 256) {
#pragma unroll
            for (int reg = 0; reg < 4; ++reg)
                Qrel[(wave * 16 + 4 * g + reg) * QRS + col] = (_Float16)acc[reg];
        }
    }

    float mrow[4], lrow[4];
    f32x4 oacc[4];
#pragma unroll
    for (int i = 0; i < 4; ++i) {
        mrow[i] = -1e30f; lrow[i] = 0.f;
        oacc[i] = (f32x4){0.f, 0.f, 0.f, 0.f};
    }

    for (int k0 = 0; k0 < S_LEN; k0 += KVBLK) {
        __syncthreads();
        {
            const int r  = tid >> 2;
            const int dq = (tid & 3) << 4;
            const float* src = Kh + (size_t)(k0 + r) * HDIM + dq;
            f32x4 f0 = *(const f32x4*)(src);
            f32x4 f1 = *(const f32x4*)(src + 4);
            f32x4 f2 = *(const f32x4*)(src + 8);
            f32x4 f3 = *(const f32x4*)(src + 12);
            half8 h0, h1;
#pragma unroll
            for (int j = 0; j < 4; ++j) {
                h0[j] = (_Float16)f0[j]; h0[j+4] = (_Float16)f1[j];
                h1[j] = (_Float16)f2[j]; h1[j+4] = (_Float16)f3[j];
            }
            const int swz = (r & 7) << 4;
            char* base = (char*)Klds;
            *(half8*)(base + ((r * 128 + dq * 2) ^ swz))      = h0;
            *(half8*)(base + ((r * 128 + dq * 2 + 16) ^ swz)) = h1;
        }
        {
            const int kv = tid & 63;
            const int dbase = (tid >> 6) << 4;
            const float* src = Vh + (size_t)(k0 + kv) * HDIM + dbase;
            f32x4 f0 = *(const f32x4*)(src);
            f32x4 f1 = *(const f32x4*)(src + 4);
            f32x4 f2 = *(const f32x4*)(src + 8);
            f32x4 f3 = *(const f32x4*)(src + 12);
            float vals[16];
#pragma unroll
            for (int j = 0; j < 4; ++j) {
                vals[j] = f0[j]; vals[4+j] = f1[j]; vals[8+j] = f2[j]; vals[12+j] = f3[j];
            }
            char* base = (char*)Vt;
#pragma unroll
            for (int i = 0; i < 16; ++i) {
                const int d = dbase + i;
                const int off = (d * 128 + kv * 2) ^ ((d & 7) << 4);
                *(_Float16*)(base + off) = (_Float16)vals[i];
            }
        }
        __syncthreads();

        f32x4 sacc[4];
#pragma unroll
        for (int n = 0; n < 4; ++n) sacc[n] = (f32x4){0.f,0.f,0.f,0.f};
#pragma unroll
        for (int kc = 0; kc < 2; ++kc) {
#pragma unroll
            for (int n = 0; n < 4; ++n) {
                const int off = (((16*n + c) * 128) + kc * 64 + g * 16) ^ ((c & 7) << 4);
                half8 bk = *(const half8*)((const char*)Klds + off);
                sacc[n] = __builtin_amdgcn_mfma_f32_16x16x32_f16(aq[kc], bk, sacc[n], 0, 0, 0);
            }
        }

        float sval[4][4];
        const int myq0 = q0 + wave * 16 + 4 * g;
#pragma unroll
        for (int n = 0; n < 4; ++n) {
            const int kpos = k0 + 16 * n + c;
#pragma unroll
            for (int reg = 0; reg < 4; ++reg) {
                int rel = kpos - (myq0 + reg);
                rel = rel < -128 ? -128 : (rel > 128 ? 128 : rel);
                const float bias = (float)Qrel[(wave*16 + 4*g + reg) * QRS + (rel + 128)];
                sval[n][reg] = sacc[n][reg] + bias;
            }
        }

        float mt[4];
#pragma unroll
        for (int reg = 0; reg < 4; ++reg) {
            float mp = fmaxf(fmaxf(sval[0][reg], sval[1][reg]),
                             fmaxf(sval[2][reg], sval[3][reg]));
#pragma unroll
            for (int msk = 1; msk < 16; msk <<= 1)
                mp = fmaxf(mp, __shfl_xor(mp, msk, 64));
            mt[reg] = mp;
        }

        float alpha[4], psum[4];
#pragma unroll
        for (int reg = 0; reg < 4; ++reg) {
            const float mn = fmaxf(mrow[reg], mt[reg]);
            alpha[reg] = __expf(mrow[reg] - mn);
            mrow[reg] = mn;
            psum[reg] = 0.f;
        }

        char* pbase = (char*)&Plds[wave][0];
#pragma unroll
        for (int n = 0; n < 4; ++n) {
#pragma unroll
            for (int reg = 0; reg < 4; ++reg) {
                const float pv = __expf(sval[n][reg] - mrow[reg]);
                psum[reg] += pv;
                const int row = 4 * g + reg;
                const int off = (row * 128 + (16 * n + c) * 2) ^ ((row & 7) << 4);
                *(_Float16*)(pbase + off) = (_Float16)pv;
            }
        }

#pragma unroll
        for (int reg = 0; reg < 4; ++reg) {
            float ps = psum[reg];
#pragma unroll
            for (int msk = 1; msk < 16; msk <<= 1)
                ps += __shfl_xor(ps, msk, 64);
            lrow[reg] = lrow[reg] * alpha[reg] + ps;
#pragma unroll
            for (int dn = 0; dn < 4; ++dn) oacc[dn][reg] *= alpha[reg];
        }

        asm volatile("s_waitcnt lgkmcnt(0)" ::: "memory");

        half8 ap[2];
#pragma unroll
        for (int kc = 0; kc < 2; ++kc) {
            const int off = (c * 128 + kc * 64 + g * 16) ^ ((c & 7) << 4);
            ap[kc] = *(const half8*)(pbase + off);
        }
#pragma unroll
        for (int kc = 0; kc < 2; ++kc) {
#pragma unroll
            for (int dn = 0; dn < 4; ++dn) {
                const int drow = 16 * dn + c;
                const int off = (drow * 128 + kc * 64 + g * 16) ^ ((c & 7) << 4);
                half8 bv = *(const half8*)((const char*)Vt + off);
                oacc[dn] = __builtin_amdgcn_mfma_f32_16x16x32_f16(ap[kc], bv, oacc[dn], 0, 0, 0);
            }
        }
    }

#pragma unroll
    for (int reg = 0; reg < 4; ++reg) {
        const float inv = 1.0f / lrow[reg];
        const int row = q0 + wave * 16 + 4 * g + reg;
        float* dst = Og + hoff + (size_t)row * HDIM + c;
#pragma unroll
        for (int dn = 0; dn < 4; ++dn)
            dst[16 * dn] = oacc[dn][reg] * inv;
    }
}

extern "C" void kernel_launch(void* const* d_in, const int* in_sizes, int n_in,
                              void* d_out, int out_size, void* d_ws, size_t ws_size,
                              hipStream_t stream) {
    const float* q   = (const float*)d_in[0];
    const float* k   = (const float*)d_in[1];
    const float* v   = (const float*)d_in[2];
    const float* rel = (const float*)d_in[3];
    float* out = (float*)d_out;
    (void)in_sizes; (void)n_in; (void)out_size;

    const size_t kv_bytes = (size_t)NBH * S_LEN * HDIM * sizeof(_Float16);  // 4 MB
    const size_t op_bytes = (size_t)1024 * 4096 * sizeof(_Float16);         // 8 MB
    const size_t ml_bytes = (size_t)1024 * 64 * sizeof(float);              // 256 KB
    const size_t need = 2 * kv_bytes + op_bytes + 2 * ml_bytes;             // ~16.5 MB

    if (ws_size >= need) {
        char* p = (char*)d_ws;
        _Float16* KhB  = (_Float16*)p;                 p += kv_bytes;
        _Float16* VpB  = (_Float16*)p;                 p += kv_bytes;
        _Float16* OpB  = (_Float16*)p;                 p += op_bytes;
        float*    MpB  = (float*)p;                    p += ml_bytes;
        float*    LpB  = (float*)p;
        convert_kv_kernel<<<dim3(1536), 256, 0, stream>>>(k, v, KhB, VpB);
        relattn_v5<<<dim3(1024), 256, 0, stream>>>(q, rel, KhB, VpB, OpB, MpB, LpB);
        combine_kernel<<<dim3(2048), 256, 0, stream>>>(OpB, MpB, LpB, out);
    } else {
        relattn_v1<<<dim3(NBH * (S_LEN / QBLK)), 256, 0, stream>>>(q, k, v, rel, out);
    }
}

// Round 6
// 73.634 us; speedup vs baseline: 1.9319x; 1.8617x over previous
//
#include <hip/hip_runtime.h>

typedef _Float16 half8 __attribute__((ext_vector_type(8)));
typedef _Float16 half4 __attribute__((ext_vector_type(4)));
typedef float f32x4 __attribute__((ext_vector_type(4)));

#define S_LEN 2048
#define HDIM 64
#define QBLK 64
#define KVBLK 64
#define NT (S_LEN / KVBLK)
#define QRS 258
#define NBH 16
#define L2E 1.44269504f
#define TSTR 72

__device__ __forceinline__ void load_lds16(const void* g, void* l) {
    __builtin_amdgcn_global_load_lds(
        (const __attribute__((address_space(1))) unsigned int*)g,
        (__attribute__((address_space(3))) unsigned int*)l, 16, 0, 0);
}

// ---- fused pre-pass ----------------------------------------------------------------
// blocks 0..1023: K fp32 -> Kh fp16 per-tile swizzled image:
//   (bh,t,kv,d) at byte (bh*32+t)*8192 + ((kv*128 + d*2) ^ ((kv&7)<<4))
//   (wave w's 16-row slice = contiguous 2KB at +w*2048)
// blocks 1024..1535: V fp32 -> Vp fp16 per-slice PV-fragment image:
//   tile t, slice w, chunk s in {0,1}, lane: 16B at bt*8192 + w*2048 + s*1024 + lane*16
//   content[j]   = V[16w+4g+j][32s + c]      (dn=2s  chunk)
//   content[4+j] = V[16w+4g+j][32s + 16 + c] (dn=2s+1 chunk)
__global__ __launch_bounds__(256)
void convert_kv_kernel(const float* __restrict__ Kg, const float* __restrict__ Vg,
                       _Float16* __restrict__ Kh, _Float16* __restrict__ Vp)
{
    __shared__ _Float16 tile[KVBLK * TSTR];
    const int bid = blockIdx.x;
    const int tid = threadIdx.x;
    if (bid < 1024) {
        const int id = bid * 256 + tid;
        const int r  = id >> 3;
        const int d0 = (id & 7) * 8;
        const float* src = Kg + (size_t)r * HDIM + d0;
        f32x4 f0 = *(const f32x4*)(src);
        f32x4 f1 = *(const f32x4*)(src + 4);
        half8 h;
#pragma unroll
        for (int j = 0; j < 4; ++j) { h[j] = (_Float16)f0[j]; h[j+4] = (_Float16)f1[j]; }
        const int bh = r >> 11, kvg = r & 2047;
        const int t = kvg >> 6, kv = kvg & 63;
        const size_t blk = (size_t)(bh * NT + t) * 8192;
        const int off = (kv * 128 + d0 * 2) ^ ((kv & 7) << 4);
        *(half8*)((char*)Kh + blk + off) = h;
    } else {
        const int bt = bid - 1024;               // bh*32 + t
        const int bh = bt >> 5, t = bt & 31;
        {
            const int kv = tid >> 2;
            const int d0 = (tid & 3) * 16;
            const float* src = Vg + ((size_t)bh * S_LEN + t * KVBLK + kv) * HDIM + d0;
            f32x4 f0 = *(const f32x4*)(src);
            f32x4 f1 = *(const f32x4*)(src + 4);
            f32x4 f2 = *(const f32x4*)(src + 8);
            f32x4 f3 = *(const f32x4*)(src + 12);
            half8 h0, h1;
#pragma unroll
            for (int j = 0; j < 4; ++j) {
                h0[j] = (_Float16)f0[j]; h0[j+4] = (_Float16)f1[j];
                h1[j] = (_Float16)f2[j]; h1[j+4] = (_Float16)f3[j];
            }
            *(half8*)&tile[kv * TSTR + d0]     = h0;
            *(half8*)&tile[kv * TSTR + d0 + 8] = h1;
        }
        __syncthreads();
        {
            const int w = tid >> 6, lane = tid & 63;
            const int c = lane & 15, g = lane >> 4;
            char* base = (char*)Vp + (size_t)bt * 8192 + w * 2048;
#pragma unroll
            for (int s = 0; s < 2; ++s) {
                half8 ch;
#pragma unroll
                for (int j = 0; j < 4; ++j) {
                    ch[j]     = tile[(16*w + 4*g + j) * TSTR + 32*s + c];
                    ch[4 + j] = tile[(16*w + 4*g + j) * TSTR + 32*s + 16 + c];
                }
                *(half8*)(base + s * 1024 + lane * 16) = ch;
            }
        }
    }
}

// ---- main attention kernel (v6: barrier-free wave-private kv slices) ---------------
// Each wave w: kv rows [16w,16w+16) of every tile; full 64q x 64d fp32 partial;
// in-LDS split-kv combine at the end.
__global__ __launch_bounds__(256, 2)
void relattn_v6(const float* __restrict__ Qg, const float* __restrict__ RELg,
                const _Float16* __restrict__ Kh, const _Float16* __restrict__ Vp,
                float* __restrict__ Og)
{
    __shared__ __attribute__((aligned(16))) char Stage[4][8192];       // 32 KB: per-wave [buf][K 2K|V 2K]; reused as combine buf
    __shared__ __attribute__((aligned(16))) _Float16 Qrel[QBLK * QRS]; // 33 KB
    __shared__ float MLds[4][64];
    __shared__ float LLds[4][64];

    const int tid  = threadIdx.x;
    const int w    = tid >> 6;
    const int lane = tid & 63;
    const int c = lane & 15;
    const int g = lane >> 4;

    const int wk = ((blockIdx.x & 7) << 6) + (blockIdx.x >> 3);  // XCD-chunked, 512%8==0
    const int bh = wk >> 5;
    const int q0 = (wk & 31) * QBLK;
    const size_t hoff = (size_t)bh * S_LEN * HDIM;

    // ---- Q fragments (B-operand per (kc,qn)), x0.125 ----
    half8 bq[2][4];
#pragma unroll
    for (int qn = 0; qn < 4; ++qn) {
        const int qrow = q0 + 16 * qn + c;
#pragma unroll
        for (int kc = 0; kc < 2; ++kc) {
            const float* src = Qg + hoff + (size_t)qrow * HDIM + kc * 32 + g * 8;
            f32x4 f0 = *(const f32x4*)(src);
            f32x4 f1 = *(const f32x4*)(src + 4);
            half8 h;
#pragma unroll
            for (int j = 0; j < 4; ++j) {
                h[j]     = (_Float16)(f0[j] * 0.125f);
                h[j + 4] = (_Float16)(f1[j] * 0.125f);
            }
            bq[kc][qn] = h;
        }
    }

    // ---- qrel build: wave w computes rows [16w..16w+16) (A-frag == bq[kc][w]) ----
#pragma unroll 1
    for (int t = 0; t < 17; ++t) {
        f32x4 acc = {0.f, 0.f, 0.f, 0.f};
        int r = t * 16 + c;
        if (r > 256) r = 256;
#pragma unroll
        for (int kc = 0; kc < 2; ++kc) {
            const float* src = RELg + (size_t)r * HDIM + kc * 32 + g * 8;
            f32x4 f0 = *(const f32x4*)(src);
            f32x4 f1 = *(const f32x4*)(src + 4);
            half8 b;
#pragma unroll
            for (int j = 0; j < 4; ++j) { b[j] = (_Float16)f0[j]; b[j+4] = (_Float16)f1[j]; }
            acc = __builtin_amdgcn_mfma_f32_16x16x32_f16(bq[kc][w], b, acc, 0, 0, 0);
        }
        const int col = t * 16 + c;
        if (col <= 256) {
#pragma unroll
            for (int reg = 0; reg < 4; ++reg)
                Qrel[(16 * w + 4 * g + reg) * QRS + col] = (_Float16)acc[reg];
        }
    }
    __syncthreads();   // the ONLY pre-loop barrier (Qrel is cross-wave)

    const _Float16* qr[4];
    float bias_lo[4], bias_hi[4];
#pragma unroll
    for (int qn = 0; qn < 4; ++qn) {
        qr[qn] = &Qrel[(16 * qn + c) * QRS];
        bias_lo[qn] = (float)qr[qn][0];
        bias_hi[qn] = (float)qr[qn][256];
    }

    half4 ones4;
#pragma unroll
    for (int j = 0; j < 4; ++j) ones4[j] = (_Float16)1.0f;

    float m[4];
    f32x4 l_acc[4];
    f32x4 oacc[4][4];
#pragma unroll
    for (int qn = 0; qn < 4; ++qn) {
        m[qn] = -1e30f;
        l_acc[qn] = (f32x4){0.f, 0.f, 0.f, 0.f};
#pragma unroll
        for (int dn = 0; dn < 4; ++dn) oacc[qn][dn] = (f32x4){0.f, 0.f, 0.f, 0.f};
    }

    const char* kimg = (const char*)Kh + (size_t)bh * NT * 8192;
    const char* vimg = (const char*)Vp + (size_t)bh * NT * 8192;
    char* Sw = &Stage[w][0];
    const int swz = (c & 7) << 4;

#define ISSUE(tt, bb) do {                                              \
        const char* kt = kimg + (size_t)(tt) * 8192 + w * 2048 + lane * 16; \
        const char* vt = vimg + (size_t)(tt) * 8192 + w * 2048 + lane * 16; \
        char* d_ = Sw + (bb) * 4096 + lane * 16;                        \
        load_lds16(kt,        d_);                                      \
        load_lds16(kt + 1024, d_ + 1024);                               \
        load_lds16(vt,        d_ + 2048);                               \
        load_lds16(vt + 1024, d_ + 3072);                               \
    } while (0)

#define BODY(t, b) do {                                                              \
        const int tn = ((t) + 1 < NT) ? (t) + 1 : (t);                               \
        ISSUE(tn, (b) ^ 1);                                                          \
        asm volatile("s_waitcnt vmcnt(4)" ::: "memory");                             \
        const char* kb = Sw + (b) * 4096;                                            \
        const int k0 = (t) * KVBLK;                                                  \
        half8 ak0 = *(const half8*)(kb + ((c * 128 + g * 16) ^ swz));                \
        half8 ak1 = *(const half8*)(kb + ((c * 128 + 64 + g * 16) ^ swz));           \
        half8 vv0 = *(const half8*)(kb + 2048 + lane * 16);                          \
        half8 vv1 = *(const half8*)(kb + 3072 + lane * 16);                          \
        f32x4 sacc[4];                                                               \
        _Pragma("unroll")                                                            \
        for (int qn = 0; qn < 4; ++qn) sacc[qn] = (f32x4){0.f,0.f,0.f,0.f};          \
        __builtin_amdgcn_s_setprio(1);                                               \
        _Pragma("unroll")                                                            \
        for (int qn = 0; qn < 4; ++qn)                                               \
            sacc[qn] = __builtin_amdgcn_mfma_f32_16x16x32_f16(ak0, bq[0][qn], sacc[qn], 0, 0, 0); \
        _Pragma("unroll")                                                            \
        for (int qn = 0; qn < 4; ++qn)                                               \
            sacc[qn] = __builtin_amdgcn_mfma_f32_16x16x32_f16(ak1, bq[1][qn], sacc[qn], 0, 0, 0); \
        __builtin_amdgcn_s_setprio(0);                                               \
        const bool band = (k0 + 192 > q0) && (k0 < q0 + 192);                        \
        float bcv[4], mtb[4];                                                        \
        if (!band) {                                                                 \
            _Pragma("unroll")                                                        \
            for (int qn = 0; qn < 4; ++qn) {                                         \
                bcv[qn] = (k0 < q0) ? bias_lo[qn] : bias_hi[qn];                     \
                float mt = fmaxf(fmaxf(sacc[qn][0], sacc[qn][1]),                    \
                                 fmaxf(sacc[qn][2], sacc[qn][3]));                   \
                mt = fmaxf(mt, __shfl_xor(mt, 16, 64));                              \
                mt = fmaxf(mt, __shfl_xor(mt, 32, 64));                              \
                mtb[qn] = mt + bcv[qn];                                              \
            }                                                                        \
        } else {                                                                     \
            _Pragma("unroll")                                                        \
            for (int qn = 0; qn < 4; ++qn) {                                         \
                bcv[qn] = 0.f;                                                       \
                const int base_qn = k0 + 16 * w + 4 * g - (q0 + 16 * qn + c) + 128;  \
                float mt = -1e30f;                                                   \
                _Pragma("unroll")                                                    \
                for (int r = 0; r < 4; ++r) {                                        \
                    int idx = base_qn + r;                                           \
                    idx = idx < 0 ? 0 : (idx > 256 ? 256 : idx);                     \
                    sacc[qn][r] += (float)qr[qn][idx];                               \
                    mt = fmaxf(mt, sacc[qn][r]);                                     \
                }                                                                    \
                mt = fmaxf(mt, __shfl_xor(mt, 16, 64));                              \
                mt = fmaxf(mt, __shfl_xor(mt, 32, 64));                              \
                mtb[qn] = mt;                                                        \
            }                                                                        \
        }                                                                            \
        const bool okd = (mtb[0] <= m[0] + 8.f) && (mtb[1] <= m[1] + 8.f) &&         \
                         (mtb[2] <= m[2] + 8.f) && (mtb[3] <= m[3] + 8.f);           \
        if (!__all(okd)) {                                                           \
            _Pragma("unroll")                                                        \
            for (int qn = 0; qn < 4; ++qn) {                                         \
                const float mnew = fmaxf(m[qn], mtb[qn]);                            \
                const float al = __builtin_amdgcn_exp2f((m[qn] - mnew) * L2E);       \
                m[qn] = mnew;                                                        \
                _Pragma("unroll")                                                    \
                for (int r = 0; r < 4; ++r) {                                        \
                    const float ar = __shfl(al, 20 * g + r, 64);                     \
                    l_acc[qn][r] *= ar;                                              \
                    _Pragma("unroll")                                                \
                    for (int dn = 0; dn < 4; ++dn) oacc[qn][dn][r] *= ar;            \
                }                                                                    \
            }                                                                        \
        }                                                                            \
        half4 p4h[4];                                                                \
        _Pragma("unroll")                                                            \
        for (int qn = 0; qn < 4; ++qn) {                                             \
            const float fold = (bcv[qn] - m[qn]) * L2E;                              \
            _Pragma("unroll")                                                        \
            for (int r = 0; r < 4; ++r)                                              \
                p4h[qn][r] = (_Float16)__builtin_amdgcn_exp2f(fmaf(sacc[qn][r], L2E, fold)); \
        }                                                                            \
        half4 vf0, vf1, vf2, vf3;                                                    \
        _Pragma("unroll")                                                            \
        for (int j = 0; j < 4; ++j) {                                                \
            vf0[j] = vv0[j]; vf1[j] = vv0[4 + j];                                    \
            vf2[j] = vv1[j]; vf3[j] = vv1[4 + j];                                    \
        }                                                                            \
        __builtin_amdgcn_s_setprio(1);                                               \
        _Pragma("unroll")                                                            \
        for (int qn = 0; qn < 4; ++qn) {                                             \
            l_acc[qn] = __builtin_amdgcn_mfma_f32_16x16x16f16(p4h[qn], ones4, l_acc[qn], 0, 0, 0); \
            oacc[qn][0] = __builtin_amdgcn_mfma_f32_16x16x16f16(p4h[qn], vf0, oacc[qn][0], 0, 0, 0); \
            oacc[qn][1] = __builtin_amdgcn_mfma_f32_16x16x16f16(p4h[qn], vf1, oacc[qn][1], 0, 0, 0); \
            oacc[qn][2] = __builtin_amdgcn_mfma_f32_16x16x16f16(p4h[qn], vf2, oacc[qn][2], 0, 0, 0); \
            oacc[qn][3] = __builtin_amdgcn_mfma_f32_16x16x16f16(p4h[qn], vf3, oacc[qn][3], 0, 0, 0); \
        }                                                                            \
        __builtin_amdgcn_s_setprio(0);                                               \
    } while (0)

    ISSUE(0, 0);
#pragma unroll 1
    for (int tt = 0; tt < NT; tt += 2) {
        BODY(tt, 0);
        BODY(tt + 1, 1);
    }
#undef BODY
#undef ISSUE
    asm volatile("s_waitcnt vmcnt(0) lgkmcnt(0)" ::: "memory");

    // ---- in-LDS split-kv combine: Stage reused as Opart[w][64 rows][64 d] fp16 ----
    {
        char* Sb = &Stage[0][0];
#pragma unroll
        for (int qn = 0; qn < 4; ++qn) {
#pragma unroll
            for (int r = 0; r < 4; ++r) {
                const int row = 16 * qn + 4 * g + r;
                const int rs = (row & 7) << 4;
#pragma unroll
                for (int dn = 0; dn < 4; ++dn) {
                    const int d = 16 * dn + c;
                    *(_Float16*)(Sb + w * 8192 + ((row * 128 + d * 2) ^ rs)) = (_Float16)oacc[qn][dn][r];
                }
            }
        }
        if (g == 0) {
#pragma unroll
            for (int qn = 0; qn < 4; ++qn) MLds[w][16 * qn + c] = m[qn];
        }
        if (c == 0) {
#pragma unroll
            for (int qn = 0; qn < 4; ++qn)
#pragma unroll
                for (int r = 0; r < 4; ++r)
                    LLds[w][16 * qn + 4 * g + r] = l_acc[qn][r];
        }
        __syncthreads();

        const int row = 16 * w + c;          // this wave combines rows [16w..16w+16)
        const int rs = (c & 7) << 4;
        float mm[4], ll[4];
#pragma unroll
        for (int wp = 0; wp < 4; ++wp) { mm[wp] = MLds[wp][row]; ll[wp] = LLds[wp][row]; }
        const float M = fmaxf(fmaxf(mm[0], mm[1]), fmaxf(mm[2], mm[3]));
        float wgt[4], den = 0.f;
#pragma unroll
        for (int wp = 0; wp < 4; ++wp) {
            wgt[wp] = __builtin_amdgcn_exp2f((mm[wp] - M) * L2E);
            den += wgt[wp] * ll[wp];
        }
        const float inv = 1.0f / den;
        float accv[16];
#pragma unroll
        for (int e = 0; e < 16; ++e) accv[e] = 0.f;
#pragma unroll
        for (int wp = 0; wp < 4; ++wp) {
            const char* ob = Sb + wp * 8192;
            half8 a  = *(const half8*)(ob + ((row * 128 + 32 * g) ^ rs));
            half8 b2 = *(const half8*)(ob + ((row * 128 + 32 * g + 16) ^ rs));
#pragma unroll
            for (int e = 0; e < 8; ++e) {
                accv[e]     += (float)a[e]  * wgt[wp];
                accv[8 + e] += (float)b2[e] * wgt[wp];
            }
        }
        float* dst = Og + hoff + (size_t)(q0 + row) * HDIM + 16 * g;
#pragma unroll
        for (int u = 0; u < 4; ++u) {
            f32x4 o;
#pragma unroll
            for (int j = 0; j < 4; ++j) o[j] = accv[4 * u + j] * inv;
            *(f32x4*)(dst + 4 * u) = o;
        }
    }
}

// ---- fallback (round-1 kernel, used if ws too small) --------------------------------
__global__ __launch_bounds__(256, 2)
void relattn_v1(const float* __restrict__ Qg, const float* __restrict__ Kg,
                const float* __restrict__ Vg, const float* __restrict__ RELg,
                float* __restrict__ Og)
{
    __shared__ _Float16 Klds[KVBLK * HDIM];
    __shared__ _Float16 Vt[HDIM * KVBLK];
    __shared__ _Float16 Plds[4][16 * KVBLK];
    __shared__ _Float16 Qrel[QBLK * QRS];

    const int tid  = threadIdx.x;
    const int wave = tid >> 6;
    const int lane = tid & 63;
    const int c = lane & 15;
    const int g = lane >> 4;

    const int bid = blockIdx.x;
    const int bh  = bid >> 5;
    const int q0  = (bid & 31) * QBLK;

    const size_t hoff = (size_t)bh * S_LEN * HDIM;
    const float* Qh = Qg + hoff;
    const float* Kh = Kg + hoff;
    const float* Vh = Vg + hoff;

    const int qrow_frag = q0 + wave * 16 + c;
    half8 aq[2];
#pragma unroll
    for (int kc = 0; kc < 2; ++kc) {
        const float* src = Qh + (size_t)qrow_frag * HDIM + kc * 32 + g * 8;
        f32x4 f0 = *(const f32x4*)(src);
        f32x4 f1 = *(const f32x4*)(src + 4);
        half8 h;
#pragma unroll
        for (int j = 0; j < 4; ++j) {
            h[j]     = (_Float16)(f0[j] * 0.125f);
            h[j + 4] = (_Float16)(f1[j] * 0.125f);
        }
        aq[kc] = h;
    }

#pragma unroll 1
    for (int t = 0; t < 17; ++t) {
        f32x4 acc = {0.f, 0.f, 0.f, 0.f};
        int r = t * 16 + c;
        if (r > 256) r = 256;
#pragma unroll
        for (int kc = 0; kc < 2; ++kc) {
            const float* src = RELg + (size_t)r * HDIM + kc * 32 + g * 8;
            f32x4 f0 = *(const f32x4*)(src);
            f32x4 f1 = *(const f32x4*)(src + 4);
            half8 b;
#pragma unroll
            for (int j = 0; j < 4; ++j) { b[j] = (_Float16)f0[j]; b[j+4] = (_Float16)f1[j]; }
            acc = __builtin_amdgcn_mfma_f32_16x16x32_f16(aq[kc], b, acc, 0, 0, 0);
        }
        const int col = t * 16 + c;
        if (col <= 256) {
#pragma unroll
            for (int reg = 0; reg < 4; ++reg)
                Qrel[(wave * 16 + 4 * g + reg) * QRS + col] = (_Float16)acc[reg];
        }
    }

    float mrow[4], lrow[4];
    f32x4 oacc[4];
#pragma unroll
    for (int i = 0; i < 4; ++i) {
        mrow[i] = -1e30f; lrow[i] = 0.f;
        oacc[i] = (f32x4){0.f, 0.f, 0.f, 0.f};
    }

    for (int k0 = 0; k0 < S_LEN; k0 += KVBLK) {
        __syncthreads();
        {
            const int r  = tid >> 2;
            const int dq = (tid & 3) << 4;
            const float* src = Kh + (size_t)(k0 + r) * HDIM + dq;
            f32x4 f0 = *(const f32x4*)(src);
            f32x4 f1 = *(const f32x4*)(src + 4);
            f32x4 f2 = *(const f32x4*)(src + 8);
            f32x4 f3 = *(const f32x4*)(src + 12);
            half8 h0, h1;
#pragma unroll
            for (int j = 0; j < 4; ++j) {
                h0[j] = (_Float16)f0[j]; h0[j+4] = (_Float16)f1[j];
                h1[j] = (_Float16)f2[j]; h1[j+4] = (_Float16)f3[j];
            }
            const int swz = (r & 7) << 4;
            char* base = (char*)Klds;
            *(half8*)(base + ((r * 128 + dq * 2) ^ swz))      = h0;
            *(half8*)(base + ((r * 128 + dq * 2 + 16) ^ swz)) = h1;
        }
        {
            const int kv = tid & 63;
            const int dbase = (tid >> 6) << 4;
            const float* src = Vh + (size_t)(k0 + kv) * HDIM + dbase;
            f32x4 f0 = *(const f32x4*)(src);
            f32x4 f1 = *(const f32x4*)(src + 4);
            f32x4 f2 = *(const f32x4*)(src + 8);
            f32x4 f3 = *(const f32x4*)(src + 12);
            float vals[16];
#pragma unroll
            for (int j = 0; j < 4; ++j) {
                vals[j] = f0[j]; vals[4+j] = f1[j]; vals[8+j] = f2[j]; vals[12+j] = f3[j];
            }
            char* base = (char*)Vt;
#pragma unroll
            for (int i = 0; i < 16; ++i) {
                const int d = dbase + i;
                const int off = (d * 128 + kv * 2) ^ ((d & 7) << 4);
                *(_Float16*)(base + off) = (_Float16)vals[i];
            }
        }
        __syncthreads();

        f32x4 sacc[4];
#pragma unroll
        for (int n = 0; n < 4; ++n) sacc[n] = (f32x4){0.f,0.f,0.f,0.f};
#pragma unroll
        for (int kc = 0; kc < 2; ++kc) {
#pragma unroll
            for (int n = 0; n < 4; ++n) {
                const int off = (((16*n + c) * 128) + kc * 64 + g * 16) ^ ((c & 7) << 4);
                half8 bk = *(const half8*)((const char*)Klds + off);
                sacc[n] = __builtin_amdgcn_mfma_f32_16x16x32_f16(aq[kc], bk, sacc[n], 0, 0, 0);
            }
        }

        float sval[4][4];
        const int myq0 = q0 + wave * 16 + 4 * g;
#pragma unroll
        for (int n = 0; n < 4; ++n) {
            const int kpos = k0 + 16 * n + c;
#pragma unroll
            for (int reg = 0; reg < 4; ++reg) {
                int rel = kpos - (myq0 + reg);
                rel = rel < -128 ? -128 : (rel > 128 ? 128 : rel);
                const float bias = (float)Qrel[(wave*16 + 4*g + reg) * QRS + (rel + 128)];
                sval[n][reg] = sacc[n][reg] + bias;
            }
        }

        float mt[4];
#pragma unroll
        for (int reg = 0; reg < 4; ++reg) {
            float mp = fmaxf(fmaxf(sval[0][reg], sval[1][reg]),
                             fmaxf(sval[2][reg], sval[3][reg]));
#pragma unroll
            for (int msk = 1; msk < 16; msk <<= 1)
                mp = fmaxf(mp, __shfl_xor(mp, msk, 64));
            mt[reg] = mp;
        }

        float alpha[4], psum[4];
#pragma unroll
        for (int reg = 0; reg < 4; ++reg) {
            const float mn = fmaxf(mrow[reg], mt[reg]);
            alpha[reg] = __expf(mrow[reg] - mn);
            mrow[reg] = mn;
            psum[reg] = 0.f;
        }

        char* pbase = (char*)&Plds[wave][0];
#pragma unroll
        for (int n = 0; n < 4; ++n) {
#pragma unroll
            for (int reg = 0; reg < 4; ++reg) {
                const float pv = __expf(sval[n][reg] - mrow[reg]);
                psum[reg] += pv;
                const int row = 4 * g + reg;
                const int off = (row * 128 + (16 * n + c) * 2) ^ ((row & 7) << 4);
                *(_Float16*)(pbase + off) = (_Float16)pv;
            }
        }

#pragma unroll
        for (int reg = 0; reg < 4; ++reg) {
            float ps = psum[reg];
#pragma unroll
            for (int msk = 1; msk < 16; msk <<= 1)
                ps += __shfl_xor(ps, msk, 64);
            lrow[reg] = lrow[reg] * alpha[reg] + ps;
#pragma unroll
            for (int dn = 0; dn < 4; ++dn) oacc[dn][reg] *= alpha[reg];
        }

        asm volatile("s_waitcnt lgkmcnt(0)" ::: "memory");

        half8 ap[2];
#pragma unroll
        for (int kc = 0; kc < 2; ++kc) {
            const int off = (c * 128 + kc * 64 + g * 16) ^ ((c & 7) << 4);
            ap[kc] = *(const half8*)(pbase + off);
        }
#pragma unroll
        for (int kc = 0; kc < 2; ++kc) {
#pragma unroll
            for (int dn = 0; dn < 4; ++dn) {
                const int drow = 16 * dn + c;
                const int off = (drow * 128 + kc * 64 + g * 16) ^ ((c & 7) << 4);
                half8 bv = *(const half8*)((const char*)Vt + off);
                oacc[dn] = __builtin_amdgcn_mfma_f32_16x16x32_f16(ap[kc], bv, oacc[dn], 0, 0, 0);
            }
        }
    }

#pragma unroll
    for (int reg = 0; reg < 4; ++reg) {
        const float inv = 1.0f / lrow[reg];
        const int row = q0 + wave * 16 + 4 * g + reg;
        float* dst = Og + hoff + (size_t)row * HDIM + c;
#pragma unroll
        for (int dn = 0; dn < 4; ++dn)
            dst[16 * dn] = oacc[dn][reg] * inv;
    }
}

extern "C" void kernel_launch(void* const* d_in, const int* in_sizes, int n_in,
                              void* d_out, int out_size, void* d_ws, size_t ws_size,
                              hipStream_t stream) {
    const float* q   = (const float*)d_in[0];
    const float* k   = (const float*)d_in[1];
    const float* v   = (const float*)d_in[2];
    const float* rel = (const float*)d_in[3];
    float* out = (float*)d_out;
    (void)in_sizes; (void)n_in; (void)out_size;

    const size_t kv_bytes = (size_t)NBH * S_LEN * HDIM * sizeof(_Float16);  // 4 MB each
    if (ws_size >= 2 * kv_bytes) {
        _Float16* KhB = (_Float16*)d_ws;
        _Float16* VpB = (_Float16*)((char*)d_ws + kv_bytes);
        convert_kv_kernel<<<dim3(1536), 256, 0, stream>>>(k, v, KhB, VpB);
        relattn_v6<<<dim3(NBH * (S_LEN / QBLK)), 256, 0, stream>>>(q, rel, KhB, VpB, out);
    } else {
        relattn_v1<<<dim3(NBH * (S_LEN / QBLK)), 256, 0, stream>>>(q, k, v, rel, out);
    }
}

// Round 7
// 58.592 us; speedup vs baseline: 2.4279x; 1.2567x over previous
//
#include <hip/hip_runtime.h>

typedef _Float16 half8 __attribute__((ext_vector_type(8)));
typedef _Float16 half4 __attribute__((ext_vector_type(4)));
typedef float f32x4 __attribute__((ext_vector_type(4)));

#define S_LEN 2048
#define HDIM 64
#define QBLK 64
#define KVBLK 64
#define NT (S_LEN / KVBLK)
#define QRS 258
#define NBH 16
#define L2E 1.44269504f
#define TSTR 72

__device__ __forceinline__ void load_lds16(const void* g, void* l) {
    __builtin_amdgcn_global_load_lds(
        (const __attribute__((address_space(1))) unsigned int*)g,
        (__attribute__((address_space(3))) unsigned int*)l, 16, 0, 0);
}

// ---- fused pre-pass ----------------------------------------------------------------
// blocks 0..1023: K fp32 -> Kh fp16 per-tile swizzled image:
//   (bh,t,kv,d) at byte (bh*32+t)*8192 + ((kv*128 + d*2) ^ ((kv&7)<<4))
// blocks 1024..1535: V fp32 -> Vp fp16 pi-permuted transposed image, NOW SWIZZLED:
//   chunk (d', u=4*kc+g) at byte bt*8192 + ((d'*128 + u*16) ^ ((d'&7)<<4))
//   content = {V[32kc+4g+r][d']}_{r=0..3} ++ {V[32kc+16+4g+r][d']}_{r=0..3}
__global__ __launch_bounds__(256)
void convert_kv_kernel(const float* __restrict__ Kg, const float* __restrict__ Vg,
                       _Float16* __restrict__ Kh, _Float16* __restrict__ Vp)
{
    __shared__ _Float16 tile[KVBLK * TSTR];
    const int bid = blockIdx.x;
    const int tid = threadIdx.x;
    if (bid < 1024) {
        const int id = bid * 256 + tid;
        const int r  = id >> 3;
        const int d0 = (id & 7) * 8;
        const float* src = Kg + (size_t)r * HDIM + d0;
        f32x4 f0 = *(const f32x4*)(src);
        f32x4 f1 = *(const f32x4*)(src + 4);
        half8 h;
#pragma unroll
        for (int j = 0; j < 4; ++j) { h[j] = (_Float16)f0[j]; h[j+4] = (_Float16)f1[j]; }
        const int bh = r >> 11, kvg = r & 2047;
        const int t = kvg >> 6, kv = kvg & 63;
        const size_t blk = (size_t)(bh * NT + t) * 8192;
        const int off = (kv * 128 + d0 * 2) ^ ((kv & 7) << 4);
        *(half8*)((char*)Kh + blk + off) = h;
    } else {
        const int bt = bid - 1024;               // bh*32 + t
        const int bh = bt >> 5, t = bt & 31;
        {
            const int kv = tid >> 2;
            const int d0 = (tid & 3) * 16;
            const float* src = Vg + ((size_t)bh * S_LEN + t * KVBLK + kv) * HDIM + d0;
            f32x4 f0 = *(const f32x4*)(src);
            f32x4 f1 = *(const f32x4*)(src + 4);
            f32x4 f2 = *(const f32x4*)(src + 8);
            f32x4 f3 = *(const f32x4*)(src + 12);
            half8 h0, h1;
#pragma unroll
            for (int j = 0; j < 4; ++j) {
                h0[j] = (_Float16)f0[j]; h0[j+4] = (_Float16)f1[j];
                h1[j] = (_Float16)f2[j]; h1[j+4] = (_Float16)f3[j];
            }
            *(half8*)&tile[kv * TSTR + d0]     = h0;
            *(half8*)&tile[kv * TSTR + d0 + 8] = h1;
        }
        __syncthreads();
        {
            const int dp = tid >> 2;             // d' = 0..63
            const int u0 = (tid & 3) * 2;
            char* base = (char*)Vp + (size_t)bt * 8192;
            const int dsw = (dp & 7) << 4;
#pragma unroll
            for (int ui = 0; ui < 2; ++ui) {
                const int u  = u0 + ui;
                const int kc = u >> 2, gg = u & 3;
                half8 ch;
#pragma unroll
                for (int r = 0; r < 4; ++r) {
                    ch[r]     = tile[(32*kc + 4*gg + r)      * TSTR + dp];
                    ch[4 + r] = tile[(32*kc + 16 + 4*gg + r) * TSTR + dp];
                }
                *(half8*)(base + ((dp * 128 + u * 16) ^ dsw)) = ch;
            }
        }
    }
}

// ---- main attention kernel (v7: 8-wave blocks, q x kv-half wave split) -------------
// Wave (qs,ks): 16 q-rows [16qs..) x 32 kv rows [32ks..) of every tile.
// One barrier per tile; staging issued after the barrier; split-kv merged in LDS.
__global__ __launch_bounds__(512, 4)
void relattn_v7(const float* __restrict__ Qg, const float* __restrict__ RELg,
                const _Float16* __restrict__ Kh, const _Float16* __restrict__ Vp,
                float* __restrict__ Og)
{
    __shared__ __attribute__((aligned(16))) _Float16 Kbuf[2][4096];    // 16 KB (also Opart at end)
    __shared__ __attribute__((aligned(16))) _Float16 Vbuf[2][4096];    // 16 KB
    __shared__ __attribute__((aligned(16))) _Float16 Qrel[QBLK * QRS]; // 33 KB
    __shared__ float MLds[2][64];
    __shared__ float LLds[2][64];

    const int tid  = threadIdx.x;
    const int wave = tid >> 6;
    const int lane = tid & 63;
    const int c  = lane & 15;
    const int g  = lane >> 4;
    const int qs = wave & 3;        // q slice: rows [16qs, 16qs+16)
    const int ks = wave >> 2;       // kv half: rows [32ks, 32ks+32) of each tile

    const int wk = ((blockIdx.x & 7) << 6) + (blockIdx.x >> 3);  // XCD-chunked, 512%8==0
    const int bh = wk >> 5;
    const int q0 = (wk & 31) * QBLK;
    const size_t hoff = (size_t)bh * S_LEN * HDIM;

    // ---- Q fragment for this wave's 16 q-rows (x0.125) ----
    const int qb0 = q0 + 16 * qs;
    half8 bq[2];
#pragma unroll
    for (int kc = 0; kc < 2; ++kc) {
        const float* src = Qg + hoff + (size_t)(qb0 + c) * HDIM + kc * 32 + g * 8;
        f32x4 f0 = *(const f32x4*)(src);
        f32x4 f1 = *(const f32x4*)(src + 4);
        half8 h;
#pragma unroll
        for (int j = 0; j < 4; ++j) {
            h[j]     = (_Float16)(f0[j] * 0.125f);
            h[j + 4] = (_Float16)(f1[j] * 0.125f);
        }
        bq[kc] = h;
    }

    // ---- qrel build (ks==0 waves only; wave qs builds rows [16qs..16qs+16)) ----
    if (ks == 0) {
#pragma unroll 1
        for (int t = 0; t < 17; ++t) {
            f32x4 acc = {0.f, 0.f, 0.f, 0.f};
            int r = t * 16 + c;
            if (r > 256) r = 256;
#pragma unroll
            for (int kc = 0; kc < 2; ++kc) {
                const float* src = RELg + (size_t)r * HDIM + kc * 32 + g * 8;
                f32x4 f0 = *(const f32x4*)(src);
                f32x4 f1 = *(const f32x4*)(src + 4);
                half8 b;
#pragma unroll
                for (int j = 0; j < 4; ++j) { b[j] = (_Float16)f0[j]; b[j+4] = (_Float16)f1[j]; }
                acc = __builtin_amdgcn_mfma_f32_16x16x32_f16(bq[kc], b, acc, 0, 0, 0);
            }
            const int col = t * 16 + c;
            if (col <= 256) {
#pragma unroll
                for (int reg = 0; reg < 4; ++reg)
                    Qrel[(16 * qs + 4 * g + reg) * QRS + col] = (_Float16)acc[reg];
            }
        }
    }

    // ---- prologue staging of tile 0 (all 512 threads: K 8KB + V 8KB) ----
    const char* kimg = (const char*)Kh + (size_t)bh * NT * 8192;
    const char* vimg = (const char*)Vp + (size_t)bh * NT * 8192;
    load_lds16(kimg + tid * 16, (char*)Kbuf + tid * 16);
    load_lds16(vimg + tid * 16, (char*)Vbuf + tid * 16);

    __syncthreads();   // Qrel visible to all waves

    const _Float16* qr = &Qrel[(16 * qs + c) * QRS];
    const float bias_lo = (float)qr[0];
    const float bias_hi = (float)qr[256];

    // loop-invariant LDS byte offsets
    const int swz = (c & 7) << 4;
    int akoff[2][2], voff[4];
#pragma unroll
    for (int n = 0; n < 2; ++n)
#pragma unroll
        for (int kc = 0; kc < 2; ++kc)
            akoff[n][kc] = (((32 * ks + 16 * n + c) * 128) + kc * 64 + g * 16) ^ swz;
#pragma unroll
    for (int dn = 0; dn < 4; ++dn)
        voff[dn] = (((16 * dn + c) * 128) + ks * 64 + g * 16) ^ swz;

    half8 ones;
#pragma unroll
    for (int j = 0; j < 8; ++j) ones[j] = (_Float16)1.0f;

    float m = -1e30f;
    f32x4 l_acc = {0.f, 0.f, 0.f, 0.f};
    f32x4 oacc[4];
#pragma unroll
    for (int i = 0; i < 4; ++i) oacc[i] = (f32x4){0.f, 0.f, 0.f, 0.f};

#define BODY(t, b) do {                                                              \
        asm volatile("s_waitcnt vmcnt(0)" ::: "memory");                             \
        __builtin_amdgcn_s_barrier();                                                \
        {                                                                            \
            const int tn = ((t) + 1 < NT) ? (t) + 1 : (t);                           \
            load_lds16(kimg + (size_t)tn * 8192 + tid * 16,                          \
                       (char*)Kbuf + ((b) ^ 1) * 8192 + tid * 16);                   \
            load_lds16(vimg + (size_t)tn * 8192 + tid * 16,                          \
                       (char*)Vbuf + ((b) ^ 1) * 8192 + tid * 16);                   \
        }                                                                            \
        const char* kb = (const char*)Kbuf + (b) * 8192;                             \
        const char* vb = (const char*)Vbuf + (b) * 8192;                             \
        const int kws = (t) * KVBLK + 32 * ks;                                       \
        half8 a00 = *(const half8*)(kb + akoff[0][0]);                               \
        half8 a01 = *(const half8*)(kb + akoff[0][1]);                               \
        half8 a10 = *(const half8*)(kb + akoff[1][0]);                               \
        half8 a11 = *(const half8*)(kb + akoff[1][1]);                               \
        f32x4 s0 = {0.f,0.f,0.f,0.f}, s1 = {0.f,0.f,0.f,0.f};                        \
        __builtin_amdgcn_s_setprio(1);                                               \
        s0 = __builtin_amdgcn_mfma_f32_16x16x32_f16(a00, bq[0], s0, 0, 0, 0);        \
        s1 = __builtin_amdgcn_mfma_f32_16x16x32_f16(a10, bq[0], s1, 0, 0, 0);        \
        s0 = __builtin_amdgcn_mfma_f32_16x16x32_f16(a01, bq[1], s0, 0, 0, 0);        \
        s1 = __builtin_amdgcn_mfma_f32_16x16x32_f16(a11, bq[1], s1, 0, 0, 0);        \
        __builtin_amdgcn_s_setprio(0);                                               \
        float bias = 0.f;                                                            \
        float lm;                                                                    \
        if (kws + 159 <= qb0) {                                                      \
            bias = bias_lo;                                                          \
            lm = fmaxf(fmaxf(fmaxf(s0[0], s0[1]), fmaxf(s0[2], s0[3])),              \
                       fmaxf(fmaxf(s1[0], s1[1]), fmaxf(s1[2], s1[3]))) + bias;      \
        } else if (kws >= qb0 + 143) {                                               \
            bias = bias_hi;                                                          \
            lm = fmaxf(fmaxf(fmaxf(s0[0], s0[1]), fmaxf(s0[2], s0[3])),              \
                       fmaxf(fmaxf(s1[0], s1[1]), fmaxf(s1[2], s1[3]))) + bias;      \
        } else {                                                                     \
            const int base_d = kws + 4 * g - (qb0 + c) + 128;                        \
            _Pragma("unroll")                                                        \
            for (int r = 0; r < 4; ++r) {                                            \
                int i0 = base_d + r;                                                 \
                i0 = i0 < 0 ? 0 : (i0 > 256 ? 256 : i0);                             \
                int i1 = base_d + 16 + r;                                            \
                i1 = i1 < 0 ? 0 : (i1 > 256 ? 256 : i1);                             \
                s0[r] += (float)qr[i0];                                              \
                s1[r] += (float)qr[i1];                                              \
            }                                                                        \
            lm = fmaxf(fmaxf(fmaxf(s0[0], s0[1]), fmaxf(s0[2], s0[3])),              \
                       fmaxf(fmaxf(s1[0], s1[1]), fmaxf(s1[2], s1[3])));             \
        }                                                                            \
        if (!__all(lm <= m + 8.f)) {                                                 \
            float mt = lm;                                                           \
            mt = fmaxf(mt, __shfl_xor(mt, 16, 64));                                  \
            mt = fmaxf(mt, __shfl_xor(mt, 32, 64));                                  \
            const float mnew = fmaxf(m, mt);                                         \
            const float al = __builtin_amdgcn_exp2f((m - mnew) * L2E);               \
            m = mnew;                                                                \
            _Pragma("unroll")                                                        \
            for (int r = 0; r < 4; ++r) {                                            \
                const float ar = __shfl(al, 20 * g + r, 64);                         \
                l_acc[r] *= ar;                                                      \
                _Pragma("unroll")                                                    \
                for (int dn = 0; dn < 4; ++dn) oacc[dn][r] *= ar;                    \
            }                                                                        \
        }                                                                            \
        const float fold = (bias - m) * L2E;                                         \
        half8 ap;                                                                    \
        _Pragma("unroll")                                                            \
        for (int r = 0; r < 4; ++r) {                                                \
            ap[r]     = (_Float16)__builtin_amdgcn_exp2f(fmaf(s0[r], L2E, fold));    \
            ap[4 + r] = (_Float16)__builtin_amdgcn_exp2f(fmaf(s1[r], L2E, fold));    \
        }                                                                            \
        half8 v0 = *(const half8*)(vb + voff[0]);                                    \
        half8 v1 = *(const half8*)(vb + voff[1]);                                    \
        half8 v2 = *(const half8*)(vb + voff[2]);                                    \
        half8 v3 = *(const half8*)(vb + voff[3]);                                    \
        __builtin_amdgcn_s_setprio(1);                                               \
        l_acc   = __builtin_amdgcn_mfma_f32_16x16x32_f16(ap, ones, l_acc, 0, 0, 0);  \
        oacc[0] = __builtin_amdgcn_mfma_f32_16x16x32_f16(ap, v0, oacc[0], 0, 0, 0);  \
        oacc[1] = __builtin_amdgcn_mfma_f32_16x16x32_f16(ap, v1, oacc[1], 0, 0, 0);  \
        oacc[2] = __builtin_amdgcn_mfma_f32_16x16x32_f16(ap, v2, oacc[2], 0, 0, 0);  \
        oacc[3] = __builtin_amdgcn_mfma_f32_16x16x32_f16(ap, v3, oacc[3], 0, 0, 0);  \
        __builtin_amdgcn_s_setprio(0);                                               \
    } while (0)

#pragma unroll 1
    for (int tt = 0; tt < NT; tt += 2) {
        BODY(tt, 0);
        BODY(tt + 1, 1);
    }
#undef BODY

    // ---- drain tail staging, then 2-way split-kv combine in LDS (reuse Kbuf) ----
    asm volatile("s_waitcnt vmcnt(0)" ::: "memory");
    __syncthreads();

    {
        char* Ob = (char*)Kbuf;   // 16 KB = 2 halves x 64 rows x 64 d fp16 (row-swizzled)
#pragma unroll
        for (int r = 0; r < 4; ++r) {
            const int row = 16 * qs + 4 * g + r;
            const int rsw = (row & 7) << 4;
#pragma unroll
            for (int dn = 0; dn < 4; ++dn)
                *(_Float16*)(Ob + ks * 8192 + ((row * 128 + (16 * dn + c) * 2) ^ rsw))
                    = (_Float16)oacc[dn][r];
        }
        if (g == 0) MLds[ks][16 * qs + c] = m;
        if (c == 0) {
#pragma unroll
            for (int r = 0; r < 4; ++r)
                LLds[ks][16 * qs + 4 * g + r] = l_acc[r];
        }
        __syncthreads();

        const int row = 16 * qs + c;         // this wave merges its 16 rows, d-half ks
        const int rsw = (c & 7) << 4;
        const float m0 = MLds[0][row], m1 = MLds[1][row];
        const float l0 = LLds[0][row], l1 = LLds[1][row];
        const float M  = fmaxf(m0, m1);
        const float w0 = __builtin_amdgcn_exp2f((m0 - M) * L2E);
        const float w1 = __builtin_amdgcn_exp2f((m1 - M) * L2E);
        const float inv = 1.0f / (l0 * w0 + l1 * w1);

        const int dof = 64 * ks + 16 * g;    // byte offset: d0 = 32ks + 8g
        half8 o0 = *(const half8*)(Ob +        ((row * 128 + dof) ^ rsw));
        half8 o1 = *(const half8*)(Ob + 8192 + ((row * 128 + dof) ^ rsw));
        float* dst = Og + hoff + (size_t)(q0 + row) * HDIM + 32 * ks + 8 * g;
        f32x4 oA, oB;
#pragma unroll
        for (int j = 0; j < 4; ++j) {
            oA[j] = ((float)o0[j]     * w0 + (float)o1[j]     * w1) * inv;
            oB[j] = ((float)o0[4 + j] * w0 + (float)o1[4 + j] * w1) * inv;
        }
        *(f32x4*)dst = oA;
        *(f32x4*)(dst + 4) = oB;
    }
}

// ---- fallback (round-1 kernel, used if ws too small) --------------------------------
__global__ __launch_bounds__(256, 2)
void relattn_v1(const float* __restrict__ Qg, const float* __restrict__ Kg,
                const float* __restrict__ Vg, const float* __restrict__ RELg,
                float* __restrict__ Og)
{
    __shared__ _Float16 Klds[KVBLK * HDIM];
    __shared__ _Float16 Vt[HDIM * KVBLK];
    __shared__ _Float16 Plds[4][16 * KVBLK];
    __shared__ _Float16 Qrel[QBLK * QRS];

    const int tid  = threadIdx.x;
    const int wave = tid >> 6;
    const int lane = tid & 63;
    const int c = lane & 15;
    const int g = lane >> 4;

    const int bid = blockIdx.x;
    const int bh  = bid >> 5;
    const int q0  = (bid & 31) * QBLK;

    const size_t hoff = (size_t)bh * S_LEN * HDIM;
    const float* Qh = Qg + hoff;
    const float* Kh = Kg + hoff;
    const float* Vh = Vg + hoff;

    const int qrow_frag = q0 + wave * 16 + c;
    half8 aq[2];
#pragma unroll
    for (int kc = 0; kc < 2; ++kc) {
        const float* src = Qh + (size_t)qrow_frag * HDIM + kc * 32 + g * 8;
        f32x4 f0 = *(const f32x4*)(src);
        f32x4 f1 = *(const f32x4*)(src + 4);
        half8 h;
#pragma unroll
        for (int j = 0; j < 4; ++j) {
            h[j]     = (_Float16)(f0[j] * 0.125f);
            h[j + 4] = (_Float16)(f1[j] * 0.125f);
        }
        aq[kc] = h;
    }

#pragma unroll 1
    for (int t = 0; t < 17; ++t) {
        f32x4 acc = {0.f, 0.f, 0.f, 0.f};
        int r = t * 16 + c;
        if (r > 256) r = 256;
#pragma unroll
        for (int kc = 0; kc < 2; ++kc) {
            const float* src = RELg + (size_t)r * HDIM + kc * 32 + g * 8;
            f32x4 f0 = *(const f32x4*)(src);
            f32x4 f1 = *(const f32x4*)(src + 4);
            half8 b;
#pragma unroll
            for (int j = 0; j < 4; ++j) { b[j] = (_Float16)f0[j]; b[j+4] = (_Float16)f1[j]; }
            acc = __builtin_amdgcn_mfma_f32_16x16x32_f16(aq[kc], b, acc, 0, 0, 0);
        }
        const int col = t * 16 + c;
        if (col <= 256) {
#pragma unroll
            for (int reg = 0; reg < 4; ++reg)
                Qrel[(wave * 16 + 4 * g + reg) * QRS + col] = (_Float16)acc[reg];
        }
    }

    float mrow[4], lrow[4];
    f32x4 oacc[4];
#pragma unroll
    for (int i = 0; i < 4; ++i) {
        mrow[i] = -1e30f; lrow[i] = 0.f;
        oacc[i] = (f32x4){0.f, 0.f, 0.f, 0.f};
    }

    for (int k0 = 0; k0 < S_LEN; k0 += KVBLK) {
        __syncthreads();
        {
            const int r  = tid >> 2;
            const int dq = (tid & 3) << 4;
            const float* src = Kh + (size_t)(k0 + r) * HDIM + dq;
            f32x4 f0 = *(const f32x4*)(src);
            f32x4 f1 = *(const f32x4*)(src + 4);
            f32x4 f2 = *(const f32x4*)(src + 8);
            f32x4 f3 = *(const f32x4*)(src + 12);
            half8 h0, h1;
#pragma unroll
            for (int j = 0; j < 4; ++j) {
                h0[j] = (_Float16)f0[j]; h0[j+4] = (_Float16)f1[j];
                h1[j] = (_Float16)f2[j]; h1[j+4] = (_Float16)f3[j];
            }
            const int swz = (r & 7) << 4;
            char* base = (char*)Klds;
            *(half8*)(base + ((r * 128 + dq * 2) ^ swz))      = h0;
            *(half8*)(base + ((r * 128 + dq * 2 + 16) ^ swz)) = h1;
        }
        {
            const int kv = tid & 63;
            const int dbase = (tid >> 6) << 4;
            const float* src = Vh + (size_t)(k0 + kv) * HDIM + dbase;
            f32x4 f0 = *(const f32x4*)(src);
            f32x4 f1 = *(const f32x4*)(src + 4);
            f32x4 f2 = *(const f32x4*)(src + 8);
            f32x4 f3 = *(const f32x4*)(src + 12);
            float vals[16];
#pragma unroll
            for (int j = 0; j < 4; ++j) {
                vals[j] = f0[j]; vals[4+j] = f1[j]; vals[8+j] = f2[j]; vals[12+j] = f3[j];
            }
            char* base = (char*)Vt;
#pragma unroll
            for (int i = 0; i < 16; ++i) {
                const int d = dbase + i;
                const int off = (d * 128 + kv * 2) ^ ((d & 7) << 4);
                *(_Float16*)(base + off) = (_Float16)vals[i];
            }
        }
        __syncthreads();

        f32x4 sacc[4];
#pragma unroll
        for (int n = 0; n < 4; ++n) sacc[n] = (f32x4){0.f,0.f,0.f,0.f};
#pragma unroll
        for (int kc = 0; kc < 2; ++kc) {
#pragma unroll
            for (int n = 0; n < 4; ++n) {
                const int off = (((16*n + c) * 128) + kc * 64 + g * 16) ^ ((c & 7) << 4);
                half8 bk = *(const half8*)((const char*)Klds + off);
                sacc[n] = __builtin_amdgcn_mfma_f32_16x16x32_f16(aq[kc], bk, sacc[n], 0, 0, 0);
            }
        }

        float sval[4][4];
        const int myq0 = q0 + wave * 16 + 4 * g;
#pragma unroll
        for (int n = 0; n < 4; ++n) {
            const int kpos = k0 + 16 * n + c;
#pragma unroll
            for (int reg = 0; reg < 4; ++reg) {
                int rel = kpos - (myq0 + reg);
                rel = rel < -128 ? -128 : (rel > 128 ? 128 : rel);
                const float bias = (float)Qrel[(wave*16 + 4*g + reg) * QRS + (rel + 128)];
                sval[n][reg] = sacc[n][reg] + bias;
            }
        }

        float mt[4];
#pragma unroll
        for (int reg = 0; reg < 4; ++reg) {
            float mp = fmaxf(fmaxf(sval[0][reg], sval[1][reg]),
                             fmaxf(sval[2][reg], sval[3][reg]));
#pragma unroll
            for (int msk = 1; msk < 16; msk <<= 1)
                mp = fmaxf(mp, __shfl_xor(mp, msk, 64));
            mt[reg] = mp;
        }

        float alpha[4], psum[4];
#pragma unroll
        for (int reg = 0; reg < 4; ++reg) {
            const float mn = fmaxf(mrow[reg], mt[reg]);
            alpha[reg] = __expf(mrow[reg] - mn);
            mrow[reg] = mn;
            psum[reg] = 0.f;
        }

        char* pbase = (char*)&Plds[wave][0];
#pragma unroll
        for (int n = 0; n < 4; ++n) {
#pragma unroll
            for (int reg = 0; reg < 4; ++reg) {
                const float pv = __expf(sval[n][reg] - mrow[reg]);
                psum[reg] += pv;
                const int row = 4 * g + reg;
                const int off = (row * 128 + (16 * n + c) * 2) ^ ((row & 7) << 4);
                *(_Float16*)(pbase + off) = (_Float16)pv;
            }
        }

#pragma unroll
        for (int reg = 0; reg < 4; ++reg) {
            float ps = psum[reg];
#pragma unroll
            for (int msk = 1; msk < 16; msk <<= 1)
                ps += __shfl_xor(ps, msk, 64);
            lrow[reg] = lrow[reg] * alpha[reg] + ps;
#pragma unroll
            for (int dn = 0; dn < 4; ++dn) oacc[dn][reg] *= alpha[reg];
        }

        asm volatile("s_waitcnt lgkmcnt(0)" ::: "memory");

        half8 ap[2];
#pragma unroll
        for (int kc = 0; kc < 2; ++kc) {
            const int off = (c * 128 + kc * 64 + g * 16) ^ ((c & 7) << 4);
            ap[kc] = *(const half8*)(pbase + off);
        }
#pragma unroll
        for (int kc = 0; kc < 2; ++kc) {
#pragma unroll
            for (int dn = 0; dn < 4; ++dn) {
                const int drow = 16 * dn + c;
                const int off = (drow * 128 + kc * 64 + g * 16) ^ ((c & 7) << 4);
                half8 bv = *(const half8*)((const char*)Vt + off);
                oacc[dn] = __builtin_amdgcn_mfma_f32_16x16x32_f16(ap[kc], bv, oacc[dn], 0, 0, 0);
            }
        }
    }

#pragma unroll
    for (int reg = 0; reg < 4; ++reg) {
        const float inv = 1.0f / lrow[reg];
        const int row = q0 + wave * 16 + 4 * g + reg;
        float* dst = Og + hoff + (size_t)row * HDIM + c;
#pragma unroll
        for (int dn = 0; dn < 4; ++dn)
            dst[16 * dn] = oacc[dn][reg] * inv;
    }
}

extern "C" void kernel_launch(void* const* d_in, const int* in_sizes, int n_in,
                              void* d_out, int out_size, void* d_ws, size_t ws_size,
                              hipStream_t stream) {
    const float* q   = (const float*)d_in[0];
    const float* k   = (const float*)d_in[1];
    const float* v   = (const float*)d_in[2];
    const float* rel = (const float*)d_in[3];
    float* out = (float*)d_out;
    (void)in_sizes; (void)n_in; (void)out_size;

    const size_t kv_bytes = (size_t)NBH * S_LEN * HDIM * sizeof(_Float16);  // 4 MB each
    if (ws_size >= 2 * kv_bytes) {
        _Float16* KhB = (_Float16*)d_ws;
        _Float16* VpB = (_Float16*)((char*)d_ws + kv_bytes);
        convert_kv_kernel<<<dim3(1536), 256, 0, stream>>>(k, v, KhB, VpB);
        relattn_v7<<<dim3(NBH * (S_LEN / QBLK)), 512, 0, stream>>>(q, rel, KhB, VpB, out);
    } else {
        relattn_v1<<<dim3(NBH * (S_LEN / QBLK)), 256, 0, stream>>>(q, k, v, rel, out);
    }
}